// Round 3
// baseline (1020.362 us; speedup 1.0000x reference)
//
#include <hip/hip_runtime.h>
#include <math.h>

#define B_ 1024
#define N_ 64
#define F_ 512

typedef const __attribute__((address_space(1))) float* gptr_t;
typedef __attribute__((address_space(3))) float* lptr_t;

__device__ __forceinline__ void gload16(const float* g, float* l) {
  __builtin_amdgcn_global_load_lds((gptr_t)g, (lptr_t)l, 16, 0, 0);
}

#define COMP(v, kk) ((kk) == 0 ? (v).x : (kk) == 1 ? (v).y : (kk) == 2 ? (v).z : (v).w)

// ---------------------------------------------------------------------------
// Kernel 1: Wh = h @ W fused GEMM, M=65536, K=512, N=512.
// 128x128 tile, 256 threads, 8x8 micro-tile with SPLIT column groups
// (cols tn*4..+3 and 64+tn*4..+3): B reads 16B-stride (2-way, free) and
// stores fully contiguous 256B/instr. Kc=16 double-buffered -> 32KB LDS ->
// 4 blocks/CU. A swizzled via pre-swizzled global source (rule #21).
// ---------------------------------------------------------------------------
__global__ __launch_bounds__(256, 4) void k_wh(const float* __restrict__ hA,
                                               const float* __restrict__ W,
                                               float* __restrict__ Wh) {
  __shared__ float As[2][128 * 16];
  __shared__ float Bs[2][16 * 128];

  const int bid = blockIdx.x;                    // 0..2047
  const int wg  = (bid & 7) * 256 + (bid >> 3);  // XCD-grouped logical id
  const int mt  = wg >> 2;                       // M-tile 0..511
  const int nt  = wg & 3;                        // N-tile 0..3
  const int t    = threadIdx.x;
  const int tm   = t >> 4;                       // rows tm*8..+7
  const int tn   = t & 15;                       // col groups tn*4 / 64+tn*4
  const int w    = t >> 6;                       // wave id
  const int lane = t & 63;

  const float* Ab = hA + (size_t)mt * 128 * F_;
  const float* Bb = W + nt * 128;

  // Staging descriptors: 8 chunks of 1KB per tile; each wave stages 2.
  int Aoff[2], Boff[2], ldsOff[2];
#pragma unroll
  for (int i = 0; i < 2; ++i) {
    int c = w + 4 * i;             // wave-uniform chunk id 0..7
    int e = c * 64 + lane;         // f4 slot in 128x4(f4) A tile
    int row = e >> 2;
    int j = e & 3;
    int jg = j ^ ((row >> 3) & 3); // inverse-swizzled global f4-column
    Aoff[i] = row * F_ + jg * 4;
    int k = e >> 5;                // B: 32 f4 per k-row
    int n4 = e & 31;
    Boff[i] = k * F_ + n4 * 4;
    ldsOff[i] = c * 256;           // floats (wave-uniform)
  }

  float acc[8][8];
#pragma unroll
  for (int i = 0; i < 8; ++i)
#pragma unroll
    for (int c = 0; c < 8; ++c) acc[i][c] = 0.f;

#define STAGE(buf, k0)                                                    \
  do {                                                                    \
    _Pragma("unroll") for (int i_ = 0; i_ < 2; ++i_)                      \
        gload16(Ab + (size_t)(k0) + Aoff[i_], &As[buf][ldsOff[i_]]);      \
    _Pragma("unroll") for (int i_ = 0; i_ < 2; ++i_)                      \
        gload16(Bb + (size_t)(k0) * F_ + Boff[i_], &Bs[buf][ldsOff[i_]]); \
  } while (0)

#define COMPUTE(buf)                                                      \
  do {                                                                    \
    const float4* Av = (const float4*)As[buf];                            \
    const float4* Bv = (const float4*)Bs[buf];                            \
    _Pragma("unroll") for (int k4 = 0; k4 < 4; ++k4) {                    \
      float4 a[8];                                                        \
      _Pragma("unroll") for (int i_ = 0; i_ < 8; ++i_)                    \
          a[i_] = Av[(tm * 8 + i_) * 4 + (k4 ^ (tm & 3))];                \
      _Pragma("unroll") for (int kk = 0; kk < 4; ++kk) {                  \
        float4 bl = Bv[(k4 * 4 + kk) * 32 + tn];                          \
        float4 bh = Bv[(k4 * 4 + kk) * 32 + 16 + tn];                     \
        _Pragma("unroll") for (int i_ = 0; i_ < 8; ++i_) {                \
          float av = COMP(a[i_], kk);                                     \
          acc[i_][0] += av * bl.x;                                        \
          acc[i_][1] += av * bl.y;                                        \
          acc[i_][2] += av * bl.z;                                        \
          acc[i_][3] += av * bl.w;                                        \
          acc[i_][4] += av * bh.x;                                        \
          acc[i_][5] += av * bh.y;                                        \
          acc[i_][6] += av * bh.z;                                        \
          acc[i_][7] += av * bh.w;                                        \
        }                                                                 \
      }                                                                   \
    }                                                                     \
  } while (0)

  STAGE(0, 0);
  __syncthreads();
#pragma unroll 1
  for (int kt = 0; kt < 32; ++kt) {
    int cur = kt & 1;
    if (kt < 31) STAGE(cur ^ 1, (kt + 1) * 16);
    COMPUTE(cur);
    __syncthreads();
  }

  float* whb = Wh + (size_t)mt * 128 * F_ + nt * 128;
#pragma unroll
  for (int i = 0; i < 8; ++i) {
    float4 v0 = make_float4(acc[i][0], acc[i][1], acc[i][2], acc[i][3]);
    float4 v1 = make_float4(acc[i][4], acc[i][5], acc[i][6], acc[i][7]);
    *(float4*)(whb + (tm * 8 + i) * F_ + tn * 4) = v0;
    *(float4*)(whb + (tm * 8 + i) * F_ + 64 + tn * 4) = v1;
  }
#undef STAGE
#undef COMPUTE
}

// ---------------------------------------------------------------------------
// Kernel 2: per-batch pipeline (unchanged). Grid = B blocks.
// ---------------------------------------------------------------------------
__global__ __launch_bounds__(256) void k_attn(const float* __restrict__ Wh,
                                              const float* __restrict__ A1,
                                              const float* __restrict__ A2,
                                              const float* __restrict__ betap,
                                              float* __restrict__ out) {
  __shared__ float sm[12736];
  float* e_s   = sm;
  float* hid_s = sm + 4160;
  float* xm_s  = sm + 4160;
  float* a_s   = sm + 8512;
  float* wh_s  = sm + 4160;
  float* mu    = sm + 12608;
  float* nrm   = sm + 12672;

  const int b = blockIdx.x;
  const int t = threadIdx.x;
  const float beta = betap[0];
  const float* whb = Wh + (size_t)b * N_ * F_;

  // ---- row means of Wh[b] ----
  {
    int n = t >> 2, q = t & 3;
    const float* row = whb + n * F_ + q * 128;
    float s = 0.f;
#pragma unroll
    for (int i = 0; i < 32; ++i) {
      float4 v = *(const float4*)(row + i * 4);
      s += v.x + v.y + v.z + v.w;
    }
    s += __shfl_xor(s, 1);
    s += __shfl_xor(s, 2);
    if (q == 0) mu[n] = s * (1.f / F_);
  }
  __syncthreads();

  // ---- cov: thread owns pairs (n = tn+16r, m = tm+16c), 4x4 ----
  const int tm = t & 15, tn = t >> 4;
  float cov[4][4];
#pragma unroll
  for (int r = 0; r < 4; ++r)
#pragma unroll
    for (int c = 0; c < 4; ++c) cov[r][c] = 0.f;

  for (int ch = 0; ch < 8; ++ch) {
#pragma unroll
    for (int i = 0; i < 4; ++i) {
      int id = t + 256 * i;
      int r = id >> 4, c4 = id & 15;
      float4 v = *(const float4*)(whb + r * F_ + ch * 64 + c4 * 4);
      float m_ = mu[r];
      v.x -= m_; v.y -= m_; v.z -= m_; v.w -= m_;
      *(float4*)(&xm_s[r * 68 + c4 * 4]) = v;
    }
    __syncthreads();
#pragma unroll
    for (int f0 = 0; f0 < 64; f0 += 4) {
      float4 xa[4], xb[4];
#pragma unroll
      for (int r = 0; r < 4; ++r) xa[r] = *(const float4*)(&xm_s[(tn + 16 * r) * 68 + f0]);
#pragma unroll
      for (int c = 0; c < 4; ++c) xb[c] = *(const float4*)(&xm_s[(tm + 16 * c) * 68 + f0]);
#pragma unroll
      for (int r = 0; r < 4; ++r)
#pragma unroll
        for (int c = 0; c < 4; ++c)
          cov[r][c] += xa[r].x * xb[c].x + xa[r].y * xb[c].y +
                       xa[r].z * xb[c].z + xa[r].w * xb[c].w;
    }
    __syncthreads();
  }

  if (tn == tm) {
#pragma unroll
    for (int r = 0; r < 4; ++r) nrm[tn + 16 * r] = sqrtf(cov[r][r]);
  }
  __syncthreads();

#pragma unroll
  for (int r = 0; r < 4; ++r) {
    int n = tn + 16 * r;
#pragma unroll
    for (int c = 0; c < 4; ++c) {
      int m = tm + 16 * c;
      float denom = nrm[n] * nrm[m] + 1e-8f;
      e_s[n * 65 + m] = beta * fabsf(cov[r][c] / denom);
    }
  }
  __syncthreads();

  // ---- MLP ----
  float adjp[4][4];
#pragma unroll
  for (int r = 0; r < 4; ++r)
#pragma unroll
    for (int c = 0; c < 4; ++c) adjp[r][c] = 0.f;

  const int rg = t >> 4;
  const int jg = t & 15;

  for (int kc = 0; kc < 4; ++kc) {
#pragma unroll
    for (int i = 0; i < 4; ++i) {
      int id = t + 256 * i;
      int m = id >> 4, c4 = id & 15;
      *(float4*)(&a_s[m * 64 + c4 * 4]) =
          *(const float4*)(A1 + (size_t)m * 256 + kc * 64 + c4 * 4);
    }
    __syncthreads();

    float h1[4][4];
#pragma unroll
    for (int rr = 0; rr < 4; ++rr)
#pragma unroll
      for (int jj = 0; jj < 4; ++jj) h1[rr][jj] = 0.f;
    for (int m = 0; m < 64; ++m) {
      float er[4];
#pragma unroll
      for (int rr = 0; rr < 4; ++rr) er[rr] = e_s[(rg * 4 + rr) * 65 + m];
      float4 a4 = *(const float4*)(&a_s[m * 64 + jg * 4]);
#pragma unroll
      for (int rr = 0; rr < 4; ++rr) {
        h1[rr][0] += er[rr] * a4.x;
        h1[rr][1] += er[rr] * a4.y;
        h1[rr][2] += er[rr] * a4.z;
        h1[rr][3] += er[rr] * a4.w;
      }
    }
#pragma unroll
    for (int rr = 0; rr < 4; ++rr) {
      float4 v = make_float4(fmaxf(h1[rr][0], 0.f), fmaxf(h1[rr][1], 0.f),
                             fmaxf(h1[rr][2], 0.f), fmaxf(h1[rr][3], 0.f));
      *(float4*)(&hid_s[(rg * 4 + rr) * 64 + jg * 4]) = v;
    }
    __syncthreads();

#pragma unroll
    for (int i = 0; i < 4; ++i) {
      int id = t + 256 * i;
      int j = id >> 4, c4 = id & 15;
      *(float4*)(&a_s[j * 64 + c4 * 4]) =
          *(const float4*)(A2 + (size_t)(kc * 64 + j) * 64 + c4 * 4);
    }
    __syncthreads();

#pragma unroll
    for (int j0 = 0; j0 < 64; j0 += 4) {
      float4 hr[4], a2v[4];
#pragma unroll
      for (int r = 0; r < 4; ++r) hr[r] = *(const float4*)(&hid_s[(tn * 4 + r) * 64 + j0]);
#pragma unroll
      for (int jj = 0; jj < 4; ++jj) a2v[jj] = *(const float4*)(&a_s[(j0 + jj) * 64 + tm * 4]);
#pragma unroll
      for (int r = 0; r < 4; ++r) {
        float hv[4] = {hr[r].x, hr[r].y, hr[r].z, hr[r].w};
#pragma unroll
        for (int jj = 0; jj < 4; ++jj) {
          adjp[r][0] += hv[jj] * a2v[jj].x;
          adjp[r][1] += hv[jj] * a2v[jj].y;
          adjp[r][2] += hv[jj] * a2v[jj].z;
          adjp[r][3] += hv[jj] * a2v[jj].w;
        }
      }
    }
    __syncthreads();
  }

  // mask
#pragma unroll
  for (int r = 0; r < 4; ++r) {
    int n = tn * 4 + r;
#pragma unroll
    for (int c = 0; c < 4; ++c) {
      int m = tm * 4 + c;
      float ev = e_s[n * 65 + m];
      float pre = ev + adjp[r][c];
      e_s[n * 65 + m] = (pre > 0.f) ? ev : -1e12f;
    }
  }
  __syncthreads();

  // softmax
  {
    int n = t >> 2, p = t & 3;
    float mx = -3.0e38f;
#pragma unroll
    for (int i = 0; i < 16; ++i) mx = fmaxf(mx, e_s[n * 65 + p * 16 + i]);
    mx = fmaxf(mx, __shfl_xor(mx, 1));
    mx = fmaxf(mx, __shfl_xor(mx, 2));
    float ev[16];
    float ssum = 0.f;
#pragma unroll
    for (int i = 0; i < 16; ++i) {
      ev[i] = expf(e_s[n * 65 + p * 16 + i] - mx);
      ssum += ev[i];
    }
    ssum += __shfl_xor(ssum, 1);
    ssum += __shfl_xor(ssum, 2);
    float inv = 1.f / ssum;
#pragma unroll
    for (int i = 0; i < 16; ++i) e_s[n * 65 + p * 16 + i] = ev[i] * inv;
  }
  __syncthreads();

  // h' = attention @ Wh
  const int jf  = t & 31;
  const int rg2 = t >> 5;
  for (int ch = 0; ch < 4; ++ch) {
#pragma unroll
    for (int i = 0; i < 8; ++i) {
      int id = t + 256 * i;
      int r = id >> 5, c4 = id & 31;
      *(float4*)(&wh_s[r * 128 + c4 * 4]) =
          *(const float4*)(whb + r * F_ + ch * 128 + c4 * 4);
    }
    __syncthreads();
    float4 acc2[8];
#pragma unroll
    for (int rr = 0; rr < 8; ++rr) acc2[rr] = make_float4(0.f, 0.f, 0.f, 0.f);
    for (int m = 0; m < 64; ++m) {
      float4 wv = *(const float4*)(&wh_s[m * 128 + jf * 4]);
#pragma unroll
      for (int rr = 0; rr < 8; ++rr) {
        float a = e_s[(rg2 * 8 + rr) * 65 + m];
        acc2[rr].x += a * wv.x;
        acc2[rr].y += a * wv.y;
        acc2[rr].z += a * wv.z;
        acc2[rr].w += a * wv.w;
      }
    }
    float* ob = out + (size_t)b * N_ * F_ + ch * 128;
#pragma unroll
    for (int rr = 0; rr < 8; ++rr)
      *(float4*)(ob + (rg2 * 8 + rr) * F_ + jf * 4) = acc2[rr];
    __syncthreads();
  }
}

extern "C" void kernel_launch(void* const* d_in, const int* in_sizes, int n_in,
                              void* d_out, int out_size, void* d_ws, size_t ws_size,
                              hipStream_t stream) {
  const float* h    = (const float*)d_in[0];
  const float* W    = (const float*)d_in[1];
  const float* beta = (const float*)d_in[2];
  const float* A1   = (const float*)d_in[3];
  const float* A2   = (const float*)d_in[4];
  float* out = (float*)d_out;
  float* Wh  = (float*)d_ws;  // B*N*F*4 = 128 MiB workspace

  k_wh<<<2048, 256, 0, stream>>>(h, W, Wh);
  k_attn<<<B_, 256, 0, stream>>>(Wh, A1, A2, beta, out);
}

// Round 4
// 691.229 us; speedup vs baseline: 1.4762x; 1.4762x over previous
//
#include <hip/hip_runtime.h>
#include <math.h>

#define B_ 1024
#define N_ 64
#define F_ 512

typedef const __attribute__((address_space(1))) float* gptr_t;
typedef __attribute__((address_space(3))) float* lptr_t;

__device__ __forceinline__ void gload16(const float* g, float* l) {
  __builtin_amdgcn_global_load_lds((gptr_t)g, (lptr_t)l, 16, 0, 0);
}

#define COMP(v, kk) ((kk) == 0 ? (v).x : (kk) == 1 ? (v).y : (kk) == 2 ? (v).z : (v).w)

// ---------------------------------------------------------------------------
// Kernel 1: Wh = h @ W fused GEMM, M=65536, K=512, N=512.
// 128x128 tile, 256 threads, 8x8 micro-tile, split column groups (tn*4 and
// 64+tn*4): B reads 16B-stride (2-way, free), stores contiguous 256B/instr.
// Kc=16 double-buffered -> 32KB LDS. launch_bounds(256,2): VGPR cap 256 so
// the 64-reg accumulator stays in registers (round 3's (256,4) capped VGPR
// at 64 and spilled acc to scratch -> 2.2GB HBM traffic).
// ---------------------------------------------------------------------------
__global__ __launch_bounds__(256, 2) void k_wh(const float* __restrict__ hA,
                                               const float* __restrict__ W,
                                               float* __restrict__ Wh) {
  __shared__ float As[2][128 * 16];
  __shared__ float Bs[2][16 * 128];

  const int bid = blockIdx.x;                    // 0..2047
  const int wg  = (bid & 7) * 256 + (bid >> 3);  // XCD-grouped logical id
  const int mt  = wg >> 2;                       // M-tile 0..511
  const int nt  = wg & 3;                        // N-tile 0..3
  const int t    = threadIdx.x;
  const int tm   = t >> 4;                       // rows tm*8..+7
  const int tn   = t & 15;                       // col groups tn*4 / 64+tn*4
  const int w    = t >> 6;                       // wave id
  const int lane = t & 63;

  const float* Ab = hA + (size_t)mt * 128 * F_;
  const float* Bb = W + nt * 128;

  // Staging descriptors: 8 chunks of 1KB per tile; each wave stages 2.
  int Aoff[2], Boff[2], ldsOff[2];
#pragma unroll
  for (int i = 0; i < 2; ++i) {
    int c = w + 4 * i;             // wave-uniform chunk id 0..7
    int e = c * 64 + lane;         // f4 slot in 128x4(f4) A tile
    int row = e >> 2;
    int j = e & 3;
    int jg = j ^ ((row >> 3) & 3); // inverse-swizzled global f4-column
    Aoff[i] = row * F_ + jg * 4;
    int k = e >> 5;                // B: 32 f4 per k-row
    int n4 = e & 31;
    Boff[i] = k * F_ + n4 * 4;
    ldsOff[i] = c * 256;           // floats (wave-uniform)
  }

  float acc[8][8];
#pragma unroll
  for (int i = 0; i < 8; ++i)
#pragma unroll
    for (int c = 0; c < 8; ++c) acc[i][c] = 0.f;

#define STAGE(buf, k0)                                                    \
  do {                                                                    \
    _Pragma("unroll") for (int i_ = 0; i_ < 2; ++i_)                      \
        gload16(Ab + (size_t)(k0) + Aoff[i_], &As[buf][ldsOff[i_]]);      \
    _Pragma("unroll") for (int i_ = 0; i_ < 2; ++i_)                      \
        gload16(Bb + (size_t)(k0) * F_ + Boff[i_], &Bs[buf][ldsOff[i_]]); \
  } while (0)

#define COMPUTE(buf)                                                      \
  do {                                                                    \
    const float4* Av = (const float4*)As[buf];                            \
    const float4* Bv = (const float4*)Bs[buf];                            \
    _Pragma("unroll") for (int k4 = 0; k4 < 4; ++k4) {                    \
      float4 a[8];                                                        \
      _Pragma("unroll") for (int i_ = 0; i_ < 8; ++i_)                    \
          a[i_] = Av[(tm * 8 + i_) * 4 + (k4 ^ (tm & 3))];                \
      _Pragma("unroll") for (int kk = 0; kk < 4; ++kk) {                  \
        float4 bl = Bv[(k4 * 4 + kk) * 32 + tn];                          \
        float4 bh = Bv[(k4 * 4 + kk) * 32 + 16 + tn];                     \
        _Pragma("unroll") for (int i_ = 0; i_ < 8; ++i_) {                \
          float av = COMP(a[i_], kk);                                     \
          acc[i_][0] += av * bl.x;                                        \
          acc[i_][1] += av * bl.y;                                        \
          acc[i_][2] += av * bl.z;                                        \
          acc[i_][3] += av * bl.w;                                        \
          acc[i_][4] += av * bh.x;                                        \
          acc[i_][5] += av * bh.y;                                        \
          acc[i_][6] += av * bh.z;                                        \
          acc[i_][7] += av * bh.w;                                        \
        }                                                                 \
      }                                                                   \
    }                                                                     \
  } while (0)

  STAGE(0, 0);
  __syncthreads();
#pragma unroll 1
  for (int kt = 0; kt < 32; ++kt) {
    int cur = kt & 1;
    if (kt < 31) STAGE(cur ^ 1, (kt + 1) * 16);
    COMPUTE(cur);
    __syncthreads();
  }

  float* whb = Wh + (size_t)mt * 128 * F_ + nt * 128;
#pragma unroll
  for (int i = 0; i < 8; ++i) {
    float4 v0 = make_float4(acc[i][0], acc[i][1], acc[i][2], acc[i][3]);
    float4 v1 = make_float4(acc[i][4], acc[i][5], acc[i][6], acc[i][7]);
    *(float4*)(whb + (tm * 8 + i) * F_ + tn * 4) = v0;
    *(float4*)(whb + (tm * 8 + i) * F_ + 64 + tn * 4) = v1;
  }
#undef STAGE
#undef COMPUTE
}

// ---------------------------------------------------------------------------
// Kernel 2: per-batch pipeline (unchanged). Grid = B blocks.
// ---------------------------------------------------------------------------
__global__ __launch_bounds__(256) void k_attn(const float* __restrict__ Wh,
                                              const float* __restrict__ A1,
                                              const float* __restrict__ A2,
                                              const float* __restrict__ betap,
                                              float* __restrict__ out) {
  __shared__ float sm[12736];
  float* e_s   = sm;
  float* hid_s = sm + 4160;
  float* xm_s  = sm + 4160;
  float* a_s   = sm + 8512;
  float* wh_s  = sm + 4160;
  float* mu    = sm + 12608;
  float* nrm   = sm + 12672;

  const int b = blockIdx.x;
  const int t = threadIdx.x;
  const float beta = betap[0];
  const float* whb = Wh + (size_t)b * N_ * F_;

  // ---- row means of Wh[b] ----
  {
    int n = t >> 2, q = t & 3;
    const float* row = whb + n * F_ + q * 128;
    float s = 0.f;
#pragma unroll
    for (int i = 0; i < 32; ++i) {
      float4 v = *(const float4*)(row + i * 4);
      s += v.x + v.y + v.z + v.w;
    }
    s += __shfl_xor(s, 1);
    s += __shfl_xor(s, 2);
    if (q == 0) mu[n] = s * (1.f / F_);
  }
  __syncthreads();

  // ---- cov: thread owns pairs (n = tn+16r, m = tm+16c), 4x4 ----
  const int tm = t & 15, tn = t >> 4;
  float cov[4][4];
#pragma unroll
  for (int r = 0; r < 4; ++r)
#pragma unroll
    for (int c = 0; c < 4; ++c) cov[r][c] = 0.f;

  for (int ch = 0; ch < 8; ++ch) {
#pragma unroll
    for (int i = 0; i < 4; ++i) {
      int id = t + 256 * i;
      int r = id >> 4, c4 = id & 15;
      float4 v = *(const float4*)(whb + r * F_ + ch * 64 + c4 * 4);
      float m_ = mu[r];
      v.x -= m_; v.y -= m_; v.z -= m_; v.w -= m_;
      *(float4*)(&xm_s[r * 68 + c4 * 4]) = v;
    }
    __syncthreads();
#pragma unroll
    for (int f0 = 0; f0 < 64; f0 += 4) {
      float4 xa[4], xb[4];
#pragma unroll
      for (int r = 0; r < 4; ++r) xa[r] = *(const float4*)(&xm_s[(tn + 16 * r) * 68 + f0]);
#pragma unroll
      for (int c = 0; c < 4; ++c) xb[c] = *(const float4*)(&xm_s[(tm + 16 * c) * 68 + f0]);
#pragma unroll
      for (int r = 0; r < 4; ++r)
#pragma unroll
        for (int c = 0; c < 4; ++c)
          cov[r][c] += xa[r].x * xb[c].x + xa[r].y * xb[c].y +
                       xa[r].z * xb[c].z + xa[r].w * xb[c].w;
    }
    __syncthreads();
  }

  if (tn == tm) {
#pragma unroll
    for (int r = 0; r < 4; ++r) nrm[tn + 16 * r] = sqrtf(cov[r][r]);
  }
  __syncthreads();

#pragma unroll
  for (int r = 0; r < 4; ++r) {
    int n = tn + 16 * r;
#pragma unroll
    for (int c = 0; c < 4; ++c) {
      int m = tm + 16 * c;
      float denom = nrm[n] * nrm[m] + 1e-8f;
      e_s[n * 65 + m] = beta * fabsf(cov[r][c] / denom);
    }
  }
  __syncthreads();

  // ---- MLP ----
  float adjp[4][4];
#pragma unroll
  for (int r = 0; r < 4; ++r)
#pragma unroll
    for (int c = 0; c < 4; ++c) adjp[r][c] = 0.f;

  const int rg = t >> 4;
  const int jg = t & 15;

  for (int kc = 0; kc < 4; ++kc) {
#pragma unroll
    for (int i = 0; i < 4; ++i) {
      int id = t + 256 * i;
      int m = id >> 4, c4 = id & 15;
      *(float4*)(&a_s[m * 64 + c4 * 4]) =
          *(const float4*)(A1 + (size_t)m * 256 + kc * 64 + c4 * 4);
    }
    __syncthreads();

    float h1[4][4];
#pragma unroll
    for (int rr = 0; rr < 4; ++rr)
#pragma unroll
      for (int jj = 0; jj < 4; ++jj) h1[rr][jj] = 0.f;
    for (int m = 0; m < 64; ++m) {
      float er[4];
#pragma unroll
      for (int rr = 0; rr < 4; ++rr) er[rr] = e_s[(rg * 4 + rr) * 65 + m];
      float4 a4 = *(const float4*)(&a_s[m * 64 + jg * 4]);
#pragma unroll
      for (int rr = 0; rr < 4; ++rr) {
        h1[rr][0] += er[rr] * a4.x;
        h1[rr][1] += er[rr] * a4.y;
        h1[rr][2] += er[rr] * a4.z;
        h1[rr][3] += er[rr] * a4.w;
      }
    }
#pragma unroll
    for (int rr = 0; rr < 4; ++rr) {
      float4 v = make_float4(fmaxf(h1[rr][0], 0.f), fmaxf(h1[rr][1], 0.f),
                             fmaxf(h1[rr][2], 0.f), fmaxf(h1[rr][3], 0.f));
      *(float4*)(&hid_s[(rg * 4 + rr) * 64 + jg * 4]) = v;
    }
    __syncthreads();

#pragma unroll
    for (int i = 0; i < 4; ++i) {
      int id = t + 256 * i;
      int j = id >> 4, c4 = id & 15;
      *(float4*)(&a_s[j * 64 + c4 * 4]) =
          *(const float4*)(A2 + (size_t)(kc * 64 + j) * 64 + c4 * 4);
    }
    __syncthreads();

#pragma unroll
    for (int j0 = 0; j0 < 64; j0 += 4) {
      float4 hr[4], a2v[4];
#pragma unroll
      for (int r = 0; r < 4; ++r) hr[r] = *(const float4*)(&hid_s[(tn * 4 + r) * 64 + j0]);
#pragma unroll
      for (int jj = 0; jj < 4; ++jj) a2v[jj] = *(const float4*)(&a_s[(j0 + jj) * 64 + tm * 4]);
#pragma unroll
      for (int r = 0; r < 4; ++r) {
        float hv[4] = {hr[r].x, hr[r].y, hr[r].z, hr[r].w};
#pragma unroll
        for (int jj = 0; jj < 4; ++jj) {
          adjp[r][0] += hv[jj] * a2v[jj].x;
          adjp[r][1] += hv[jj] * a2v[jj].y;
          adjp[r][2] += hv[jj] * a2v[jj].z;
          adjp[r][3] += hv[jj] * a2v[jj].w;
        }
      }
    }
    __syncthreads();
  }

  // mask
#pragma unroll
  for (int r = 0; r < 4; ++r) {
    int n = tn * 4 + r;
#pragma unroll
    for (int c = 0; c < 4; ++c) {
      int m = tm * 4 + c;
      float ev = e_s[n * 65 + m];
      float pre = ev + adjp[r][c];
      e_s[n * 65 + m] = (pre > 0.f) ? ev : -1e12f;
    }
  }
  __syncthreads();

  // softmax
  {
    int n = t >> 2, p = t & 3;
    float mx = -3.0e38f;
#pragma unroll
    for (int i = 0; i < 16; ++i) mx = fmaxf(mx, e_s[n * 65 + p * 16 + i]);
    mx = fmaxf(mx, __shfl_xor(mx, 1));
    mx = fmaxf(mx, __shfl_xor(mx, 2));
    float ev[16];
    float ssum = 0.f;
#pragma unroll
    for (int i = 0; i < 16; ++i) {
      ev[i] = expf(e_s[n * 65 + p * 16 + i] - mx);
      ssum += ev[i];
    }
    ssum += __shfl_xor(ssum, 1);
    ssum += __shfl_xor(ssum, 2);
    float inv = 1.f / ssum;
#pragma unroll
    for (int i = 0; i < 16; ++i) e_s[n * 65 + p * 16 + i] = ev[i] * inv;
  }
  __syncthreads();

  // h' = attention @ Wh
  const int jf  = t & 31;
  const int rg2 = t >> 5;
  for (int ch = 0; ch < 4; ++ch) {
#pragma unroll
    for (int i = 0; i < 8; ++i) {
      int id = t + 256 * i;
      int r = id >> 5, c4 = id & 31;
      *(float4*)(&wh_s[r * 128 + c4 * 4]) =
          *(const float4*)(whb + r * F_ + ch * 128 + c4 * 4);
    }
    __syncthreads();
    float4 acc2[8];
#pragma unroll
    for (int rr = 0; rr < 8; ++rr) acc2[rr] = make_float4(0.f, 0.f, 0.f, 0.f);
    for (int m = 0; m < 64; ++m) {
      float4 wv = *(const float4*)(&wh_s[m * 128 + jf * 4]);
#pragma unroll
      for (int rr = 0; rr < 8; ++rr) {
        float a = e_s[(rg2 * 8 + rr) * 65 + m];
        acc2[rr].x += a * wv.x;
        acc2[rr].y += a * wv.y;
        acc2[rr].z += a * wv.z;
        acc2[rr].w += a * wv.w;
      }
    }
    float* ob = out + (size_t)b * N_ * F_ + ch * 128;
#pragma unroll
    for (int rr = 0; rr < 8; ++rr)
      *(float4*)(ob + (rg2 * 8 + rr) * F_ + jf * 4) = acc2[rr];
    __syncthreads();
  }
}

extern "C" void kernel_launch(void* const* d_in, const int* in_sizes, int n_in,
                              void* d_out, int out_size, void* d_ws, size_t ws_size,
                              hipStream_t stream) {
  const float* h    = (const float*)d_in[0];
  const float* W    = (const float*)d_in[1];
  const float* beta = (const float*)d_in[2];
  const float* A1   = (const float*)d_in[3];
  const float* A2   = (const float*)d_in[4];
  float* out = (float*)d_out;
  float* Wh  = (float*)d_ws;  // B*N*F*4 = 128 MiB workspace

  k_wh<<<2048, 256, 0, stream>>>(h, W, Wh);
  k_attn<<<B_, 256, 0, stream>>>(Wh, A1, A2, beta, out);
}

// Round 5
// 455.652 us; speedup vs baseline: 2.2393x; 1.5170x over previous
//
#include <hip/hip_runtime.h>
#include <math.h>

#define B_ 1024
#define N_ 64
#define F_ 512

typedef const __attribute__((address_space(1))) float* gptr_t;
typedef __attribute__((address_space(3))) float* lptr_t;
typedef _Float16 half_t;
typedef half_t half8 __attribute__((ext_vector_type(8)));
typedef float f32x4 __attribute__((ext_vector_type(4)));

__device__ __forceinline__ void gload16(const float* g, float* l) {
  __builtin_amdgcn_global_load_lds((gptr_t)g, (lptr_t)l, 16, 0, 0);
}

// ---------------------------------------------------------------------------
// Kernel 0: pre-split W (scaled x512) into f16 hi/lo, TRANSPOSED [n][k] with
// bank-swizzled k-octet layout (pos = octet ^ ((n^(n>>1))&3) within each
// 32-k chunk). Output lives in d_out's first 1MB (k_attn overwrites later).
// ---------------------------------------------------------------------------
__global__ __launch_bounds__(256) void k_split_w(const float* __restrict__ W,
                                                 half_t* __restrict__ wt_hi,
                                                 half_t* __restrict__ wt_lo) {
  int idx = blockIdx.x * 256 + threadIdx.x;  // 0..262143
  int k = idx >> 9, n = idx & 511;           // coalesced read over n
  float wv = W[idx] * 512.0f;
  half_t hh = (half_t)wv;
  half_t hl = (half_t)(wv - (float)hh);
  int f = (n ^ (n >> 1)) & 3;
  int pos = ((k >> 3) & 3) ^ f;
  int addr = n * 512 + (k & ~31) + (pos << 3) + (k & 7);
  wt_hi[addr] = hh;
  wt_lo[addr] = hl;
}

// ---------------------------------------------------------------------------
// Kernel 1: Wh = h @ W via f16x3 split-MFMA (ah*bh + ah*bl + al*bh).
// 128x128 tile, 4 waves (2x2 of 64x64), mfma_f32_16x16x32_f16, Kc=32
// double-buffered (64KB LDS). A staged fp32 via global_load_lds with
// XOR-pre-swizzled source; split to f16 in registers (scaled x16).
// B staged pre-split f16 (x512). Store scales by 2^-13 (exact).
// ---------------------------------------------------------------------------
__global__ __launch_bounds__(256, 2) void k_wh(const float* __restrict__ hA,
                                               const half_t* __restrict__ WTh,
                                               const half_t* __restrict__ WTl,
                                               float* __restrict__ Wh) {
  __shared__ float  As[2][128 * 32];   // 16KB x2
  __shared__ half_t Bh[2][128 * 32];   // 8KB x2
  __shared__ half_t Bl[2][128 * 32];   // 8KB x2

  const int bid = blockIdx.x;                    // 0..2047
  const int wg  = (bid & 7) * 256 + (bid >> 3);  // XCD-grouped
  const int mt  = wg >> 2;                       // M-tile 0..511
  const int nt  = wg & 3;                        // N-tile 0..3
  const int t = threadIdx.x;
  const int w = t >> 6, lane = t & 63;
  const int wr = w >> 1, wc = w & 1;             // wave 64x64 sub-tile
  const int lr = lane & 15, ko = lane >> 4;      // frag row/col, k-octet

  const float* Ab = hA + (size_t)mt * 128 * F_;
  const int n0 = nt * 128;

  // A staging: 1024 f4-slots, 4/thread; source column pre-swizzled.
  int Asrc[4], Alds[4];
#pragma unroll
  for (int i = 0; i < 4; ++i) {
    int s = t + 256 * i;
    int row = s >> 3, j = s & 7;
    int jg = j ^ (row & 7);
    Asrc[i] = row * F_ + jg * 4;
    Alds[i] = s * 4;
  }
  // B staging: 512 16B-slots per buffer, 2/thread (hi and lo same offsets).
  int Bsrc[2], Blds[2];
#pragma unroll
  for (int i = 0; i < 2; ++i) {
    int s = t + 256 * i;
    int n = s >> 2, sl = s & 3;
    Bsrc[i] = (n0 + n) * 512 + sl * 8;  // halfs
    Blds[i] = s * 8;                    // halfs
  }

  f32x4 acc[4][4];
#pragma unroll
  for (int i = 0; i < 4; ++i)
#pragma unroll
    for (int j = 0; j < 4; ++j) acc[i][j] = (f32x4){0.f, 0.f, 0.f, 0.f};

#define STAGE(buf, k0)                                                       \
  do {                                                                       \
    _Pragma("unroll") for (int i_ = 0; i_ < 4; ++i_)                         \
        gload16(Ab + (size_t)(k0) + Asrc[i_], &As[buf][Alds[i_]]);           \
    _Pragma("unroll") for (int i_ = 0; i_ < 2; ++i_)                         \
        gload16((const float*)(WTh + (size_t)(k0) + Bsrc[i_]),               \
                (float*)&Bh[buf][Blds[i_]]);                                 \
    _Pragma("unroll") for (int i_ = 0; i_ < 2; ++i_)                         \
        gload16((const float*)(WTl + (size_t)(k0) + Bsrc[i_]),               \
                (float*)&Bl[buf][Blds[i_]]);                                 \
  } while (0)

#define COMPUTE(buf)                                                         \
  do {                                                                       \
    half8 bhf[4], blf[4];                                                    \
    _Pragma("unroll") for (int j = 0; j < 4; ++j) {                          \
      int nb = wc * 64 + j * 16 + lr;                                        \
      int p = ko ^ ((nb ^ (nb >> 1)) & 3);                                   \
      bhf[j] = *(const half8*)&Bh[buf][nb * 32 + p * 8];                     \
      blf[j] = *(const half8*)&Bl[buf][nb * 32 + p * 8];                     \
    }                                                                        \
    _Pragma("unroll") for (int i = 0; i < 4; ++i) {                          \
      int r = wr * 64 + i * 16 + lr;                                         \
      int p0 = (2 * ko) ^ (r & 7), p1 = (2 * ko + 1) ^ (r & 7);              \
      f32x4 x0 = *(const f32x4*)&As[buf][r * 32 + p0 * 4];                   \
      f32x4 x1 = *(const f32x4*)&As[buf][r * 32 + p1 * 4];                   \
      half8 ah, al;                                                          \
      _Pragma("unroll") for (int q = 0; q < 4; ++q) {                        \
        float xs = x0[q] * 16.0f;                                            \
        half_t hh = (half_t)xs;                                              \
        ah[q] = hh; al[q] = (half_t)(xs - (float)hh);                        \
      }                                                                      \
      _Pragma("unroll") for (int q = 0; q < 4; ++q) {                        \
        float xs = x1[q] * 16.0f;                                            \
        half_t hh = (half_t)xs;                                              \
        ah[4 + q] = hh; al[4 + q] = (half_t)(xs - (float)hh);                \
      }                                                                      \
      _Pragma("unroll") for (int j = 0; j < 4; ++j) {                        \
        acc[i][j] = __builtin_amdgcn_mfma_f32_16x16x32_f16(ah, bhf[j],       \
                                                           acc[i][j], 0, 0, 0); \
        acc[i][j] = __builtin_amdgcn_mfma_f32_16x16x32_f16(ah, blf[j],       \
                                                           acc[i][j], 0, 0, 0); \
        acc[i][j] = __builtin_amdgcn_mfma_f32_16x16x32_f16(al, bhf[j],       \
                                                           acc[i][j], 0, 0, 0); \
      }                                                                      \
    }                                                                        \
  } while (0)

  STAGE(0, 0);
  __syncthreads();
#pragma unroll 1
  for (int kt = 0; kt < 16; ++kt) {
    int cur = kt & 1;
    if (kt < 15) STAGE(cur ^ 1, (kt + 1) * 32);
    COMPUTE(cur);
    __syncthreads();
  }

  const float sc = 1.0f / 8192.0f;  // undo x16 * x512 (exact)
  float* whb = Wh + ((size_t)mt * 128 + wr * 64) * F_ + n0 + wc * 64;
#pragma unroll
  for (int i = 0; i < 4; ++i) {
#pragma unroll
    for (int rr = 0; rr < 4; ++rr) {
      int row = i * 16 + ko * 4 + rr;
#pragma unroll
      for (int j = 0; j < 4; ++j)
        whb[row * F_ + j * 16 + lr] = acc[i][j][rr] * sc;
    }
  }
#undef STAGE
#undef COMPUTE
}

// ---------------------------------------------------------------------------
// Kernel 2: per-batch pipeline (unchanged). Grid = B blocks.
// ---------------------------------------------------------------------------
__global__ __launch_bounds__(256) void k_attn(const float* __restrict__ Wh,
                                              const float* __restrict__ A1,
                                              const float* __restrict__ A2,
                                              const float* __restrict__ betap,
                                              float* __restrict__ out) {
  __shared__ float sm[12736];
  float* e_s   = sm;
  float* hid_s = sm + 4160;
  float* xm_s  = sm + 4160;
  float* a_s   = sm + 8512;
  float* wh_s  = sm + 4160;
  float* mu    = sm + 12608;
  float* nrm   = sm + 12672;

  const int b = blockIdx.x;
  const int t = threadIdx.x;
  const float beta = betap[0];
  const float* whb = Wh + (size_t)b * N_ * F_;

  // ---- row means of Wh[b] ----
  {
    int n = t >> 2, q = t & 3;
    const float* row = whb + n * F_ + q * 128;
    float s = 0.f;
#pragma unroll
    for (int i = 0; i < 32; ++i) {
      float4 v = *(const float4*)(row + i * 4);
      s += v.x + v.y + v.z + v.w;
    }
    s += __shfl_xor(s, 1);
    s += __shfl_xor(s, 2);
    if (q == 0) mu[n] = s * (1.f / F_);
  }
  __syncthreads();

  // ---- cov: thread owns pairs (n = tn+16r, m = tm+16c), 4x4 ----
  const int tm = t & 15, tn = t >> 4;
  float cov[4][4];
#pragma unroll
  for (int r = 0; r < 4; ++r)
#pragma unroll
    for (int c = 0; c < 4; ++c) cov[r][c] = 0.f;

  for (int ch = 0; ch < 8; ++ch) {
#pragma unroll
    for (int i = 0; i < 4; ++i) {
      int id = t + 256 * i;
      int r = id >> 4, c4 = id & 15;
      float4 v = *(const float4*)(whb + r * F_ + ch * 64 + c4 * 4);
      float m_ = mu[r];
      v.x -= m_; v.y -= m_; v.z -= m_; v.w -= m_;
      *(float4*)(&xm_s[r * 68 + c4 * 4]) = v;
    }
    __syncthreads();
#pragma unroll
    for (int f0 = 0; f0 < 64; f0 += 4) {
      float4 xa[4], xb[4];
#pragma unroll
      for (int r = 0; r < 4; ++r) xa[r] = *(const float4*)(&xm_s[(tn + 16 * r) * 68 + f0]);
#pragma unroll
      for (int c = 0; c < 4; ++c) xb[c] = *(const float4*)(&xm_s[(tm + 16 * c) * 68 + f0]);
#pragma unroll
      for (int r = 0; r < 4; ++r)
#pragma unroll
        for (int c = 0; c < 4; ++c)
          cov[r][c] += xa[r].x * xb[c].x + xa[r].y * xb[c].y +
                       xa[r].z * xb[c].z + xa[r].w * xb[c].w;
    }
    __syncthreads();
  }

  if (tn == tm) {
#pragma unroll
    for (int r = 0; r < 4; ++r) nrm[tn + 16 * r] = sqrtf(cov[r][r]);
  }
  __syncthreads();

#pragma unroll
  for (int r = 0; r < 4; ++r) {
    int n = tn + 16 * r;
#pragma unroll
    for (int c = 0; c < 4; ++c) {
      int m = tm + 16 * c;
      float denom = nrm[n] * nrm[m] + 1e-8f;
      e_s[n * 65 + m] = beta * fabsf(cov[r][c] / denom);
    }
  }
  __syncthreads();

  // ---- MLP ----
  float adjp[4][4];
#pragma unroll
  for (int r = 0; r < 4; ++r)
#pragma unroll
    for (int c = 0; c < 4; ++c) adjp[r][c] = 0.f;

  const int rg = t >> 4;
  const int jg = t & 15;

  for (int kc = 0; kc < 4; ++kc) {
#pragma unroll
    for (int i = 0; i < 4; ++i) {
      int id = t + 256 * i;
      int m = id >> 4, c4 = id & 15;
      *(float4*)(&a_s[m * 64 + c4 * 4]) =
          *(const float4*)(A1 + (size_t)m * 256 + kc * 64 + c4 * 4);
    }
    __syncthreads();

    float h1[4][4];
#pragma unroll
    for (int rr = 0; rr < 4; ++rr)
#pragma unroll
      for (int jj = 0; jj < 4; ++jj) h1[rr][jj] = 0.f;
    for (int m = 0; m < 64; ++m) {
      float er[4];
#pragma unroll
      for (int rr = 0; rr < 4; ++rr) er[rr] = e_s[(rg * 4 + rr) * 65 + m];
      float4 a4 = *(const float4*)(&a_s[m * 64 + jg * 4]);
#pragma unroll
      for (int rr = 0; rr < 4; ++rr) {
        h1[rr][0] += er[rr] * a4.x;
        h1[rr][1] += er[rr] * a4.y;
        h1[rr][2] += er[rr] * a4.z;
        h1[rr][3] += er[rr] * a4.w;
      }
    }
#pragma unroll
    for (int rr = 0; rr < 4; ++rr) {
      float4 v = make_float4(fmaxf(h1[rr][0], 0.f), fmaxf(h1[rr][1], 0.f),
                             fmaxf(h1[rr][2], 0.f), fmaxf(h1[rr][3], 0.f));
      *(float4*)(&hid_s[(rg * 4 + rr) * 64 + jg * 4]) = v;
    }
    __syncthreads();

#pragma unroll
    for (int i = 0; i < 4; ++i) {
      int id = t + 256 * i;
      int j = id >> 4, c4 = id & 15;
      *(float4*)(&a_s[j * 64 + c4 * 4]) =
          *(const float4*)(A2 + (size_t)(kc * 64 + j) * 64 + c4 * 4);
    }
    __syncthreads();

#pragma unroll
    for (int j0 = 0; j0 < 64; j0 += 4) {
      float4 hr[4], a2v[4];
#pragma unroll
      for (int r = 0; r < 4; ++r) hr[r] = *(const float4*)(&hid_s[(tn * 4 + r) * 64 + j0]);
#pragma unroll
      for (int jj = 0; jj < 4; ++jj) a2v[jj] = *(const float4*)(&a_s[(j0 + jj) * 64 + tm * 4]);
#pragma unroll
      for (int r = 0; r < 4; ++r) {
        float hv[4] = {hr[r].x, hr[r].y, hr[r].z, hr[r].w};
#pragma unroll
        for (int jj = 0; jj < 4; ++jj) {
          adjp[r][0] += hv[jj] * a2v[jj].x;
          adjp[r][1] += hv[jj] * a2v[jj].y;
          adjp[r][2] += hv[jj] * a2v[jj].z;
          adjp[r][3] += hv[jj] * a2v[jj].w;
        }
      }
    }
    __syncthreads();
  }

  // mask
#pragma unroll
  for (int r = 0; r < 4; ++r) {
    int n = tn * 4 + r;
#pragma unroll
    for (int c = 0; c < 4; ++c) {
      int m = tm * 4 + c;
      float ev = e_s[n * 65 + m];
      float pre = ev + adjp[r][c];
      e_s[n * 65 + m] = (pre > 0.f) ? ev : -1e12f;
    }
  }
  __syncthreads();

  // softmax
  {
    int n = t >> 2, p = t & 3;
    float mx = -3.0e38f;
#pragma unroll
    for (int i = 0; i < 16; ++i) mx = fmaxf(mx, e_s[n * 65 + p * 16 + i]);
    mx = fmaxf(mx, __shfl_xor(mx, 1));
    mx = fmaxf(mx, __shfl_xor(mx, 2));
    float ev[16];
    float ssum = 0.f;
#pragma unroll
    for (int i = 0; i < 16; ++i) {
      ev[i] = expf(e_s[n * 65 + p * 16 + i] - mx);
      ssum += ev[i];
    }
    ssum += __shfl_xor(ssum, 1);
    ssum += __shfl_xor(ssum, 2);
    float inv = 1.f / ssum;
#pragma unroll
    for (int i = 0; i < 16; ++i) e_s[n * 65 + p * 16 + i] = ev[i] * inv;
  }
  __syncthreads();

  // h' = attention @ Wh
  const int jf  = t & 31;
  const int rg2 = t >> 5;
  for (int ch = 0; ch < 4; ++ch) {
#pragma unroll
    for (int i = 0; i < 8; ++i) {
      int id = t + 256 * i;
      int r = id >> 5, c4 = id & 31;
      *(float4*)(&wh_s[r * 128 + c4 * 4]) =
          *(const float4*)(whb + r * F_ + ch * 128 + c4 * 4);
    }
    __syncthreads();
    float4 acc2[8];
#pragma unroll
    for (int rr = 0; rr < 8; ++rr) acc2[rr] = make_float4(0.f, 0.f, 0.f, 0.f);
    for (int m = 0; m < 64; ++m) {
      float4 wv = *(const float4*)(&wh_s[m * 128 + jf * 4]);
#pragma unroll
      for (int rr = 0; rr < 8; ++rr) {
        float a = e_s[(rg2 * 8 + rr) * 65 + m];
        acc2[rr].x += a * wv.x;
        acc2[rr].y += a * wv.y;
        acc2[rr].z += a * wv.z;
        acc2[rr].w += a * wv.w;
      }
    }
    float* ob = out + (size_t)b * N_ * F_ + ch * 128;
#pragma unroll
    for (int rr = 0; rr < 8; ++rr)
      *(float4*)(ob + (rg2 * 8 + rr) * F_ + jf * 4) = acc2[rr];
    __syncthreads();
  }
}

extern "C" void kernel_launch(void* const* d_in, const int* in_sizes, int n_in,
                              void* d_out, int out_size, void* d_ws, size_t ws_size,
                              hipStream_t stream) {
  const float* h    = (const float*)d_in[0];
  const float* W    = (const float*)d_in[1];
  const float* beta = (const float*)d_in[2];
  const float* A1   = (const float*)d_in[3];
  const float* A2   = (const float*)d_in[4];
  float* out = (float*)d_out;
  float* Wh  = (float*)d_ws;  // B*N*F*4 = 128 MiB workspace

  // W split tables live in d_out's first 1MB; k_wh consumes them before
  // k_attn overwrites d_out (stream-ordered, rebuilt every call).
  half_t* wt_hi = (half_t*)d_out;
  half_t* wt_lo = wt_hi + 512 * 512;

  k_split_w<<<1024, 256, 0, stream>>>(W, wt_hi, wt_lo);
  k_wh<<<2048, 256, 0, stream>>>(h, wt_hi, wt_lo, Wh);
  k_attn<<<B_, 256, 0, stream>>>(Wh, A1, A2, beta, out);
}

// Round 6
// 321.687 us; speedup vs baseline: 3.1719x; 1.4164x over previous
//
#include <hip/hip_runtime.h>
#include <math.h>

#define B_ 1024
#define N_ 64
#define F_ 512

typedef const __attribute__((address_space(1))) float* gptr_t;
typedef __attribute__((address_space(3))) float* lptr_t;
typedef _Float16 half_t;
typedef half_t half8 __attribute__((ext_vector_type(8)));
typedef half_t half4 __attribute__((ext_vector_type(4)));
typedef float f32x4 __attribute__((ext_vector_type(4)));

__device__ __forceinline__ void gload16(const float* g, float* l) {
  __builtin_amdgcn_global_load_lds((gptr_t)g, (lptr_t)l, 16, 0, 0);
}

// swizzled LDS addresses (halves): octet-XOR keeps b128 frag reads 2-way max
#define XMI(n, f) ((n) * 128 + (((((f) >> 3) ^ ((n) & 7))) << 3) + ((f) & 7))
#define SQI(n, m) ((n) * 64 + (((((m) >> 3) ^ ((n) & 7))) << 3) + ((m) & 7))

// ---------------------------------------------------------------------------
// Kernel 0: pre-split W (x512) into f16 hi/lo, transposed + swizzled.
// Tables live in d_out's first 1MB; consumed entirely by k_wh (stream-ordered
// before k_attn writes out), so no race.
// ---------------------------------------------------------------------------
__global__ __launch_bounds__(256) void k_split_w(const float* __restrict__ W,
                                                 half_t* __restrict__ wt_hi,
                                                 half_t* __restrict__ wt_lo) {
  int idx = blockIdx.x * 256 + threadIdx.x;  // 0..262143
  int k = idx >> 9, n = idx & 511;
  float wv = W[idx] * 512.0f;
  half_t hh = (half_t)wv;
  half_t hl = (half_t)(wv - (float)hh);
  int f = (n ^ (n >> 1)) & 3;
  int pos = ((k >> 3) & 3) ^ f;
  int addr = n * 512 + (k & ~31) + (pos << 3) + (k & 7);
  wt_hi[addr] = hh;
  wt_lo[addr] = hl;
}

// ---------------------------------------------------------------------------
// Kernel 1: Wh = h @ W via f16x3 split-MFMA (unchanged from round 4).
// ---------------------------------------------------------------------------
__global__ __launch_bounds__(256, 2) void k_wh(const float* __restrict__ hA,
                                               const half_t* __restrict__ WTh,
                                               const half_t* __restrict__ WTl,
                                               float* __restrict__ Wh) {
  __shared__ float  As[2][128 * 32];
  __shared__ half_t Bh[2][128 * 32];
  __shared__ half_t Bl[2][128 * 32];

  const int bid = blockIdx.x;
  const int wg  = (bid & 7) * 256 + (bid >> 3);
  const int mt  = wg >> 2;
  const int nt  = wg & 3;
  const int t = threadIdx.x;
  const int w = t >> 6, lane = t & 63;
  const int wr = w >> 1, wc = w & 1;
  const int lr = lane & 15, ko = lane >> 4;

  const float* Ab = hA + (size_t)mt * 128 * F_;
  const int n0 = nt * 128;

  int Asrc[4], Alds[4];
#pragma unroll
  for (int i = 0; i < 4; ++i) {
    int s = t + 256 * i;
    int row = s >> 3, j = s & 7;
    int jg = j ^ (row & 7);
    Asrc[i] = row * F_ + jg * 4;
    Alds[i] = s * 4;
  }
  int Bsrc[2], Blds[2];
#pragma unroll
  for (int i = 0; i < 2; ++i) {
    int s = t + 256 * i;
    int n = s >> 2, sl = s & 3;
    Bsrc[i] = (n0 + n) * 512 + sl * 8;
    Blds[i] = s * 8;
  }

  f32x4 acc[4][4];
#pragma unroll
  for (int i = 0; i < 4; ++i)
#pragma unroll
    for (int j = 0; j < 4; ++j) acc[i][j] = (f32x4){0.f, 0.f, 0.f, 0.f};

#define STAGE(buf, k0)                                                       \
  do {                                                                       \
    _Pragma("unroll") for (int i_ = 0; i_ < 4; ++i_)                         \
        gload16(Ab + (size_t)(k0) + Asrc[i_], &As[buf][Alds[i_]]);           \
    _Pragma("unroll") for (int i_ = 0; i_ < 2; ++i_)                         \
        gload16((const float*)(WTh + (size_t)(k0) + Bsrc[i_]),               \
                (float*)&Bh[buf][Blds[i_]]);                                 \
    _Pragma("unroll") for (int i_ = 0; i_ < 2; ++i_)                         \
        gload16((const float*)(WTl + (size_t)(k0) + Bsrc[i_]),               \
                (float*)&Bl[buf][Blds[i_]]);                                 \
  } while (0)

#define COMPUTE(buf)                                                         \
  do {                                                                       \
    half8 bhf[4], blf[4];                                                    \
    _Pragma("unroll") for (int j = 0; j < 4; ++j) {                          \
      int nb = wc * 64 + j * 16 + lr;                                        \
      int p = ko ^ ((nb ^ (nb >> 1)) & 3);                                   \
      bhf[j] = *(const half8*)&Bh[buf][nb * 32 + p * 8];                     \
      blf[j] = *(const half8*)&Bl[buf][nb * 32 + p * 8];                     \
    }                                                                        \
    _Pragma("unroll") for (int i = 0; i < 4; ++i) {                          \
      int r = wr * 64 + i * 16 + lr;                                         \
      int p0 = (2 * ko) ^ (r & 7), p1 = (2 * ko + 1) ^ (r & 7);              \
      f32x4 x0 = *(const f32x4*)&As[buf][r * 32 + p0 * 4];                   \
      f32x4 x1 = *(const f32x4*)&As[buf][r * 32 + p1 * 4];                   \
      half8 ah, al;                                                          \
      _Pragma("unroll") for (int q = 0; q < 4; ++q) {                        \
        float xs = x0[q] * 16.0f;                                            \
        half_t hh = (half_t)xs;                                              \
        ah[q] = hh; al[q] = (half_t)(xs - (float)hh);                        \
      }                                                                      \
      _Pragma("unroll") for (int q = 0; q < 4; ++q) {                        \
        float xs = x1[q] * 16.0f;                                            \
        half_t hh = (half_t)xs;                                              \
        ah[4 + q] = hh; al[4 + q] = (half_t)(xs - (float)hh);                \
      }                                                                      \
      _Pragma("unroll") for (int j = 0; j < 4; ++j) {                        \
        acc[i][j] = __builtin_amdgcn_mfma_f32_16x16x32_f16(ah, bhf[j],       \
                                                           acc[i][j], 0, 0, 0); \
        acc[i][j] = __builtin_amdgcn_mfma_f32_16x16x32_f16(ah, blf[j],       \
                                                           acc[i][j], 0, 0, 0); \
        acc[i][j] = __builtin_amdgcn_mfma_f32_16x16x32_f16(al, bhf[j],       \
                                                           acc[i][j], 0, 0, 0); \
      }                                                                      \
    }                                                                        \
  } while (0)

  STAGE(0, 0);
  __syncthreads();
#pragma unroll 1
  for (int kt = 0; kt < 16; ++kt) {
    int cur = kt & 1;
    if (kt < 15) STAGE(cur ^ 1, (kt + 1) * 32);
    COMPUTE(cur);
    __syncthreads();
  }

  const float sc = 1.0f / 8192.0f;
  float* whb = Wh + ((size_t)mt * 128 + wr * 64) * F_ + n0 + wc * 64;
#pragma unroll
  for (int i = 0; i < 4; ++i) {
#pragma unroll
    for (int rr = 0; rr < 4; ++rr) {
      int row = i * 16 + ko * 4 + rr;
#pragma unroll
      for (int j = 0; j < 4; ++j)
        whb[row * F_ + j * 16 + lr] = acc[i][j][rr] * sc;
    }
  }
#undef STAGE
#undef COMPUTE
}

// ---------------------------------------------------------------------------
// Kernel 2: per-batch pipeline, ALL matmuls via f16x3 split-MFMA.
// 1 batch/block, 256 thr, 4 waves; wave w owns n-rows w*16..+15.
// LDS pool 49664B -> 3 blocks/CU:
//   region A sm[0..4096):     e_h/e_l  -> at_h/at_l (after MLP)
//   region B sm[4096..12288): xm_h/xm_l (cov) -> hid_h/l + ab_h/l (MLP)
//                             -> wt_h/wt_l (PV)
//   mu @12288, nrm @12352.
// Scalings (exact pow2): xm x16 => cov acc x256 (EPS x256); e x16,
// A1/A2 x64 => adjp = acc * 2^-16; probs/Wh unscaled for PV.
// ---------------------------------------------------------------------------
__global__ __launch_bounds__(256) void k_attn(const float* __restrict__ Wh,
                                              const float* __restrict__ A1,
                                              const float* __restrict__ A2,
                                              const float* __restrict__ betap,
                                              float* __restrict__ out) {
  __shared__ float sm[12416];
  half_t* e_h   = (half_t*)sm;
  half_t* e_l   = e_h + 4096;
  half_t* xm_h  = (half_t*)(sm + 4096);
  half_t* xm_l  = xm_h + 8192;
  half_t* hid_h = (half_t*)(sm + 4096);
  half_t* hid_l = (half_t*)(sm + 6144);
  half_t* ab_h  = (half_t*)(sm + 8192);
  half_t* ab_l  = (half_t*)(sm + 10240);
  half_t* at_h  = (half_t*)sm;
  half_t* at_l  = at_h + 4096;
  half_t* wt_h  = (half_t*)(sm + 4096);
  half_t* wt_l  = (half_t*)(sm + 8192);
  float* mu  = sm + 12288;
  float* nrm = sm + 12352;

  const int b = blockIdx.x;
  const int t = threadIdx.x;
  const int w = t >> 6, lane = t & 63;
  const int lr = lane & 15, ko = lane >> 4;
  const float beta = betap[0];
  const float* whb = Wh + (size_t)b * N_ * F_;

  // ---- phase 1: row means ----
  {
    int n = t >> 2, q = t & 3;
    const float* row = whb + n * F_ + q * 128;
    float s = 0.f;
#pragma unroll
    for (int i = 0; i < 32; ++i) {
      float4 v = *(const float4*)(row + i * 4);
      s += v.x + v.y + v.z + v.w;
    }
    s += __shfl_xor(s, 1);
    s += __shfl_xor(s, 2);
    if (q == 0) mu[n] = s * (1.f / F_);
  }
  __syncthreads();

  // ---- phase 2: cov = Xm @ Xm^T via MFMA, 4 k-chunks of 128 ----
  f32x4 covA[4];
#pragma unroll
  for (int j = 0; j < 4; ++j) covA[j] = (f32x4){0.f, 0.f, 0.f, 0.f};

#pragma unroll 1
  for (int c = 0; c < 4; ++c) {
    // stage centered, x16, split chunk [64][128]
#pragma unroll
    for (int i = 0; i < 8; ++i) {
      int id = t + 256 * i;
      int n = id >> 5, c4 = id & 31;
      float4 v = *(const float4*)(whb + n * F_ + c * 128 + c4 * 4);
      float m_ = mu[n];
      float x0 = (v.x - m_) * 16.f, x1 = (v.y - m_) * 16.f;
      float x2 = (v.z - m_) * 16.f, x3 = (v.w - m_) * 16.f;
      half4 hh, hl;
      hh[0] = (half_t)x0; hl[0] = (half_t)(x0 - (float)hh[0]);
      hh[1] = (half_t)x1; hl[1] = (half_t)(x1 - (float)hh[1]);
      hh[2] = (half_t)x2; hl[2] = (half_t)(x2 - (float)hh[2]);
      hh[3] = (half_t)x3; hl[3] = (half_t)(x3 - (float)hh[3]);
      int ad = n * 128 + (((c4 >> 1) ^ (n & 7)) << 3) + (c4 & 1) * 4;
      *(half4*)&xm_h[ad] = hh;
      *(half4*)&xm_l[ad] = hl;
    }
    __syncthreads();
#pragma unroll
    for (int s = 0; s < 4; ++s) {
      int ra = w * 16 + lr;
      half8 ah = *(const half8*)&xm_h[XMI(ra, (s * 4 + ko) * 8)];
      half8 al = *(const half8*)&xm_l[XMI(ra, (s * 4 + ko) * 8)];
#pragma unroll
      for (int j = 0; j < 4; ++j) {
        int rb = j * 16 + lr;
        half8 bh = *(const half8*)&xm_h[XMI(rb, (s * 4 + ko) * 8)];
        half8 bl = *(const half8*)&xm_l[XMI(rb, (s * 4 + ko) * 8)];
        covA[j] = __builtin_amdgcn_mfma_f32_16x16x32_f16(ah, bh, covA[j], 0, 0, 0);
        covA[j] = __builtin_amdgcn_mfma_f32_16x16x32_f16(ah, bl, covA[j], 0, 0, 0);
        covA[j] = __builtin_amdgcn_mfma_f32_16x16x32_f16(al, bh, covA[j], 0, 0, 0);
      }
    }
    __syncthreads();
  }

  // ---- phase 3: norms from diagonal (tile j == w, lanes lc == 4ko+r) ----
#pragma unroll
  for (int r = 0; r < 4; ++r)
    if (lr == 4 * ko + r) nrm[w * 16 + lr] = sqrtf(covA[w][r]);
  __syncthreads();

  // ---- phase 4: e = beta*|corr| in regs (C-layout) + split to LDS ----
  float e32[4][4];  // [m-tile][reg]
#pragma unroll
  for (int j = 0; j < 4; ++j) {
#pragma unroll
    for (int r = 0; r < 4; ++r) {
      int n = w * 16 + 4 * ko + r;
      int m = j * 16 + lr;
      float denom = nrm[n] * nrm[m] + 2.56e-6f;  // (16nrm)(16nrm)+256*1e-8
      float e = beta * fabsf(covA[j][r] / denom);
      e32[j][r] = e;
      float es = e * 16.f;
      half_t hh = (half_t)es;
      e_h[SQI(n, m)] = hh;
      e_l[SQI(n, m)] = (half_t)(es - (float)hh);
    }
  }
  __syncthreads();

  // ---- phase 5: MLP via MFMA, K-chunked over 4 j-chunks of 64 ----
  f32x4 adj[4];
#pragma unroll
  for (int j = 0; j < 4; ++j) adj[j] = (f32x4){0.f, 0.f, 0.f, 0.f};

#pragma unroll 1
  for (int jc = 0; jc < 4; ++jc) {
    // stage A1 chunk transposed+split: ab[j_local][m], x64
#pragma unroll
    for (int i = 0; i < 4; ++i) {
      int id = t + 256 * i;
      int m = id >> 4, c4 = id & 15;
      float4 v = *(const float4*)(A1 + (size_t)m * 256 + jc * 64 + c4 * 4);
#pragma unroll
      for (int q = 0; q < 4; ++q) {
        float x = ((const float*)&v)[q] * 64.f;
        half_t hh = (half_t)x;
        int jl = c4 * 4 + q;
        ab_h[SQI(jl, m)] = hh;
        ab_l[SQI(jl, m)] = (half_t)(x - (float)hh);
      }
    }
    __syncthreads();

    // layer1: hid = relu(e @ A1chunk)
    f32x4 h1[4];
#pragma unroll
    for (int j = 0; j < 4; ++j) h1[j] = (f32x4){0.f, 0.f, 0.f, 0.f};
#pragma unroll
    for (int s = 0; s < 2; ++s) {
      int ra = w * 16 + lr;
      half8 ah = *(const half8*)&e_h[SQI(ra, (s * 4 + ko) * 8)];
      half8 al = *(const half8*)&e_l[SQI(ra, (s * 4 + ko) * 8)];
#pragma unroll
      for (int jt = 0; jt < 4; ++jt) {
        int jl = jt * 16 + lr;
        half8 bh = *(const half8*)&ab_h[SQI(jl, (s * 4 + ko) * 8)];
        half8 bl = *(const half8*)&ab_l[SQI(jl, (s * 4 + ko) * 8)];
        h1[jt] = __builtin_amdgcn_mfma_f32_16x16x32_f16(ah, bh, h1[jt], 0, 0, 0);
        h1[jt] = __builtin_amdgcn_mfma_f32_16x16x32_f16(ah, bl, h1[jt], 0, 0, 0);
        h1[jt] = __builtin_amdgcn_mfma_f32_16x16x32_f16(al, bh, h1[jt], 0, 0, 0);
      }
    }
    // relu + split -> hid (C-layout: col=lr -> j, row=4ko+r -> n-local)
#pragma unroll
    for (int jt = 0; jt < 4; ++jt) {
#pragma unroll
      for (int r = 0; r < 4; ++r) {
        float x = fmaxf(h1[jt][r], 0.f);
        int n = w * 16 + 4 * ko + r;
        int jl = jt * 16 + lr;
        half_t hh = (half_t)x;
        hid_h[SQI(n, jl)] = hh;
        hid_l[SQI(n, jl)] = (half_t)(x - (float)hh);
      }
    }
    __syncthreads();

    // stage A2 chunk: ab[m][k_local], x64 (overwrites a1 chunk)
#pragma unroll
    for (int i = 0; i < 4; ++i) {
      int id = t + 256 * i;
      int kl = id >> 4, c4 = id & 15;
      float4 v = *(const float4*)(A2 + (size_t)(jc * 64 + kl) * 64 + c4 * 4);
#pragma unroll
      for (int q = 0; q < 4; ++q) {
        float x = ((const float*)&v)[q] * 64.f;
        half_t hh = (half_t)x;
        int m = c4 * 4 + q;
        ab_h[SQI(m, kl)] = hh;
        ab_l[SQI(m, kl)] = (half_t)(x - (float)hh);
      }
    }
    __syncthreads();

    // layer2: adj += hid @ A2chunk
#pragma unroll
    for (int s = 0; s < 2; ++s) {
      int ra = w * 16 + lr;
      half8 ah = *(const half8*)&hid_h[SQI(ra, (s * 4 + ko) * 8)];
      half8 al = *(const half8*)&hid_l[SQI(ra, (s * 4 + ko) * 8)];
#pragma unroll
      for (int mt = 0; mt < 4; ++mt) {
        int m = mt * 16 + lr;
        half8 bh = *(const half8*)&ab_h[SQI(m, (s * 4 + ko) * 8)];
        half8 bl = *(const half8*)&ab_l[SQI(m, (s * 4 + ko) * 8)];
        adj[mt] = __builtin_amdgcn_mfma_f32_16x16x32_f16(ah, bh, adj[mt], 0, 0, 0);
        adj[mt] = __builtin_amdgcn_mfma_f32_16x16x32_f16(ah, bl, adj[mt], 0, 0, 0);
        adj[mt] = __builtin_amdgcn_mfma_f32_16x16x32_f16(al, bh, adj[mt], 0, 0, 0);
      }
    }
    __syncthreads();
  }

  // ---- phase 6: mask + row-softmax in regs, split probs -> at_hl ----
  {
    float p[4][4];
#pragma unroll
    for (int r = 0; r < 4; ++r) {
      float mx = -3.0e38f;
#pragma unroll
      for (int mt = 0; mt < 4; ++mt) {
        float pre = e32[mt][r] + adj[mt][r] * (1.f / 65536.f);
        p[mt][r] = (pre > 0.f) ? e32[mt][r] : -1e12f;
        mx = fmaxf(mx, p[mt][r]);
      }
      mx = fmaxf(mx, __shfl_xor(mx, 1));
      mx = fmaxf(mx, __shfl_xor(mx, 2));
      mx = fmaxf(mx, __shfl_xor(mx, 4));
      mx = fmaxf(mx, __shfl_xor(mx, 8));
      float ssum = 0.f;
#pragma unroll
      for (int mt = 0; mt < 4; ++mt) {
        p[mt][r] = expf(p[mt][r] - mx);
        ssum += p[mt][r];
      }
      ssum += __shfl_xor(ssum, 1);
      ssum += __shfl_xor(ssum, 2);
      ssum += __shfl_xor(ssum, 4);
      ssum += __shfl_xor(ssum, 8);
      float inv = 1.f / ssum;
      int n = w * 16 + 4 * ko + r;
#pragma unroll
      for (int mt = 0; mt < 4; ++mt) {
        float pv = p[mt][r] * inv;
        int m = mt * 16 + lr;
        half_t hh = (half_t)pv;
        at_h[SQI(n, m)] = hh;
        at_l[SQI(n, m)] = (half_t)(pv - (float)hh);
      }
    }
  }

  // ---- phase 7: out = attn @ Wh via MFMA, 4 f-chunks of 128 ----
#pragma unroll 1
  for (int fc = 0; fc < 4; ++fc) {
    __syncthreads();  // at_hl writes done / previous chunk reads done
    // stage Wh chunk transposed+split: wt[f_local][m]
#pragma unroll
    for (int i = 0; i < 8; ++i) {
      int id = t + 256 * i;
      int m = id >> 5, c4 = id & 31;
      float4 v = *(const float4*)(whb + m * F_ + fc * 128 + c4 * 4);
#pragma unroll
      for (int q = 0; q < 4; ++q) {
        float x = ((const float*)&v)[q];
        half_t hh = (half_t)x;
        int f = c4 * 4 + q;
        int ad = f * 64 + ((((m >> 3) ^ (f & 7))) << 3) + (m & 7);
        wt_h[ad] = hh;
        wt_l[ad] = (half_t)(x - (float)hh);
      }
    }
    __syncthreads();

    half8 aah[2], aal[2];
#pragma unroll
    for (int s = 0; s < 2; ++s) {
      int n = w * 16 + lr;
      aah[s] = *(const half8*)&at_h[SQI(n, (s * 4 + ko) * 8)];
      aal[s] = *(const half8*)&at_l[SQI(n, (s * 4 + ko) * 8)];
    }
#pragma unroll
    for (int ft = 0; ft < 8; ++ft) {
      f32x4 po = (f32x4){0.f, 0.f, 0.f, 0.f};
#pragma unroll
      for (int s = 0; s < 2; ++s) {
        int fl = ft * 16 + lr;
        int ad = fl * 64 + (((((s * 4 + ko)) ^ (fl & 7))) << 3);
        half8 bh = *(const half8*)&wt_h[ad];
        half8 bl = *(const half8*)&wt_l[ad];
        po = __builtin_amdgcn_mfma_f32_16x16x32_f16(aah[s], bh, po, 0, 0, 0);
        po = __builtin_amdgcn_mfma_f32_16x16x32_f16(aah[s], bl, po, 0, 0, 0);
        po = __builtin_amdgcn_mfma_f32_16x16x32_f16(aal[s], bh, po, 0, 0, 0);
      }
      int fg = fc * 128 + ft * 16 + lr;
#pragma unroll
      for (int r = 0; r < 4; ++r) {
        int n = w * 16 + 4 * ko + r;
        out[(size_t)b * N_ * F_ + n * F_ + fg] = po[r];
      }
    }
  }
}

extern "C" void kernel_launch(void* const* d_in, const int* in_sizes, int n_in,
                              void* d_out, int out_size, void* d_ws, size_t ws_size,
                              hipStream_t stream) {
  const float* h    = (const float*)d_in[0];
  const float* W    = (const float*)d_in[1];
  const float* beta = (const float*)d_in[2];
  const float* A1   = (const float*)d_in[3];
  const float* A2   = (const float*)d_in[4];
  float* out = (float*)d_out;
  float* Wh  = (float*)d_ws;  // 128 MiB workspace

  half_t* wt_hi = (half_t*)d_out;
  half_t* wt_lo = wt_hi + 512 * 512;

  k_split_w<<<1024, 256, 0, stream>>>(W, wt_hi, wt_lo);
  k_wh<<<2048, 256, 0, stream>>>(h, wt_hi, wt_lo, Wh);
  k_attn<<<B_, 256, 0, stream>>>(Wh, A1, A2, beta, out);
}

// Round 9
// 299.091 us; speedup vs baseline: 3.4115x; 1.0755x over previous
//
#include <hip/hip_runtime.h>
#include <math.h>

#define B_ 1024
#define N_ 64
#define F_ 512

typedef const __attribute__((address_space(1))) float* gptr_t;
typedef __attribute__((address_space(3))) float* lptr_t;
typedef _Float16 half_t;
typedef half_t half8 __attribute__((ext_vector_type(8)));
typedef half_t half4 __attribute__((ext_vector_type(4)));
typedef float f32x4 __attribute__((ext_vector_type(4)));

__device__ __forceinline__ void gload16(const float* g, float* l) {
  __builtin_amdgcn_global_load_lds((gptr_t)g, (lptr_t)l, 16, 0, 0);
}

// swizzled LDS addresses (halves): octet-XOR keeps b128 frag reads 2-way max
#define XMI(n, f) ((n) * 128 + (((((f) >> 3) ^ ((n) >> 0 & 7))) << 3) + ((f) & 7))
#define SQI(n, m) ((n) * 64 + (((((m) >> 3) ^ ((n) & 7))) << 3) + ((m) & 7))

// ---------------------------------------------------------------------------
// Kernel 0: pre-split W (x512) into f16 hi/lo, transposed + swizzled.
// ---------------------------------------------------------------------------
__global__ __launch_bounds__(256) void k_split_w(const float* __restrict__ W,
                                                 half_t* __restrict__ wt_hi,
                                                 half_t* __restrict__ wt_lo) {
  int idx = blockIdx.x * 256 + threadIdx.x;  // 0..262143
  int k = idx >> 9, n = idx & 511;
  float wv = W[idx] * 512.0f;
  half_t hh = (half_t)wv;
  half_t hl = (half_t)(wv - (float)hh);
  int f = (n ^ (n >> 1)) & 3;
  int pos = ((k >> 3) & 3) ^ f;
  int addr = n * 512 + (k & ~31) + (pos << 3) + (k & 7);
  wt_hi[addr] = hh;
  wt_lo[addr] = hl;
}

// ---------------------------------------------------------------------------
// Kernel 1: Wh = h @ W via f16x3 split-MFMA (verbatim from the passing round).
// ---------------------------------------------------------------------------
__global__ __launch_bounds__(256, 2) void k_wh(const float* __restrict__ hA,
                                               const half_t* __restrict__ WTh,
                                               const half_t* __restrict__ WTl,
                                               float* __restrict__ Wh) {
  __shared__ float  As[2][128 * 32];
  __shared__ half_t Bh[2][128 * 32];
  __shared__ half_t Bl[2][128 * 32];

  const int bid = blockIdx.x;
  const int wg  = (bid & 7) * 256 + (bid >> 3);
  const int mt  = wg >> 2;
  const int nt  = wg & 3;
  const int t = threadIdx.x;
  const int w = t >> 6, lane = t & 63;
  const int wr = w >> 1, wc = w & 1;
  const int lr = lane & 15, ko = lane >> 4;

  const float* Ab = hA + (size_t)mt * 128 * F_;
  const int n0 = nt * 128;

  int Asrc[4], Alds[4];
#pragma unroll
  for (int i = 0; i < 4; ++i) {
    int s = t + 256 * i;
    int row = s >> 3, j = s & 7;
    int jg = j ^ (row & 7);
    Asrc[i] = row * F_ + jg * 4;
    Alds[i] = s * 4;
  }
  int Bsrc[2], Blds[2];
#pragma unroll
  for (int i = 0; i < 2; ++i) {
    int s = t + 256 * i;
    int n = s >> 2, sl = s & 3;
    Bsrc[i] = (n0 + n) * 512 + sl * 8;
    Blds[i] = s * 8;
  }

  f32x4 acc[4][4];
#pragma unroll
  for (int i = 0; i < 4; ++i)
#pragma unroll
    for (int j = 0; j < 4; ++j) acc[i][j] = (f32x4){0.f, 0.f, 0.f, 0.f};

#define STAGE(buf, k0)                                                       \
  do {                                                                       \
    _Pragma("unroll") for (int i_ = 0; i_ < 4; ++i_)                         \
        gload16(Ab + (size_t)(k0) + Asrc[i_], &As[buf][Alds[i_]]);           \
    _Pragma("unroll") for (int i_ = 0; i_ < 2; ++i_)                         \
        gload16((const float*)(WTh + (size_t)(k0) + Bsrc[i_]),               \
                (float*)&Bh[buf][Blds[i_]]);                                 \
    _Pragma("unroll") for (int i_ = 0; i_ < 2; ++i_)                         \
        gload16((const float*)(WTl + (size_t)(k0) + Bsrc[i_]),               \
                (float*)&Bl[buf][Blds[i_]]);                                 \
  } while (0)

#define COMPUTE(buf)                                                         \
  do {                                                                       \
    half8 bhf[4], blf[4];                                                    \
    _Pragma("unroll") for (int j = 0; j < 4; ++j) {                          \
      int nb = wc * 64 + j * 16 + lr;                                        \
      int p = ko ^ ((nb ^ (nb >> 1)) & 3);                                   \
      bhf[j] = *(const half8*)&Bh[buf][nb * 32 + p * 8];                     \
      blf[j] = *(const half8*)&Bl[buf][nb * 32 + p * 8];                     \
    }                                                                        \
    _Pragma("unroll") for (int i = 0; i < 4; ++i) {                          \
      int r = wr * 64 + i * 16 + lr;                                         \
      int p0 = (2 * ko) ^ (r & 7), p1 = (2 * ko + 1) ^ (r & 7);              \
      f32x4 x0 = *(const f32x4*)&As[buf][r * 32 + p0 * 4];                   \
      f32x4 x1 = *(const f32x4*)&As[buf][r * 32 + p1 * 4];                   \
      half8 ah, al;                                                          \
      _Pragma("unroll") for (int q = 0; q < 4; ++q) {                        \
        float xs = x0[q] * 16.0f;                                            \
        half_t hh = (half_t)xs;                                              \
        ah[q] = hh; al[q] = (half_t)(xs - (float)hh);                        \
      }                                                                      \
      _Pragma("unroll") for (int q = 0; q < 4; ++q) {                        \
        float xs = x1[q] * 16.0f;                                            \
        half_t hh = (half_t)xs;                                              \
        ah[4 + q] = hh; al[4 + q] = (half_t)(xs - (float)hh);                \
      }                                                                      \
      _Pragma("unroll") for (int j = 0; j < 4; ++j) {                        \
        acc[i][j] = __builtin_amdgcn_mfma_f32_16x16x32_f16(ah, bhf[j],       \
                                                           acc[i][j], 0, 0, 0); \
        acc[i][j] = __builtin_amdgcn_mfma_f32_16x16x32_f16(ah, blf[j],       \
                                                           acc[i][j], 0, 0, 0); \
        acc[i][j] = __builtin_amdgcn_mfma_f32_16x16x32_f16(al, bhf[j],       \
                                                           acc[i][j], 0, 0, 0); \
      }                                                                      \
    }                                                                        \
  } while (0)

  STAGE(0, 0);
  __syncthreads();
#pragma unroll 1
  for (int kt = 0; kt < 16; ++kt) {
    int cur = kt & 1;
    if (kt < 15) STAGE(cur ^ 1, (kt + 1) * 32);
    COMPUTE(cur);
    __syncthreads();
  }

  const float sc = 1.0f / 8192.0f;
  float* whb = Wh + ((size_t)mt * 128 + wr * 64) * F_ + n0 + wc * 64;
#pragma unroll
  for (int i = 0; i < 4; ++i) {
#pragma unroll
    for (int rr = 0; rr < 4; ++rr) {
      int row = i * 16 + ko * 4 + rr;
#pragma unroll
      for (int j = 0; j < 4; ++j)
        whb[row * F_ + j * 16 + lr] = acc[i][j][rr] * sc;
    }
  }
#undef STAGE
#undef COMPUTE
}

// ---------------------------------------------------------------------------
// Kernel 2: the PASSING round-6 k_attn verbatim, with EXACTLY ONE change:
// the A1/A2 staging loops use coalesced column reads + conflict-free half8
// stores (bit-identical LDS content to the scalar originals).
// ---------------------------------------------------------------------------
__global__ __launch_bounds__(256) void k_attn(const float* __restrict__ Wh,
                                              const float* __restrict__ A1,
                                              const float* __restrict__ A2,
                                              const float* __restrict__ betap,
                                              float* __restrict__ out) {
  __shared__ float sm[12416];
  half_t* e_h   = (half_t*)sm;
  half_t* e_l   = e_h + 4096;
  half_t* xm_h  = (half_t*)(sm + 4096);
  half_t* xm_l  = xm_h + 8192;
  half_t* hid_h = (half_t*)(sm + 4096);
  half_t* hid_l = (half_t*)(sm + 6144);
  half_t* ab_h  = (half_t*)(sm + 8192);
  half_t* ab_l  = (half_t*)(sm + 10240);
  half_t* at_h  = (half_t*)sm;
  half_t* at_l  = at_h + 4096;
  half_t* wt_h  = (half_t*)(sm + 4096);
  half_t* wt_l  = (half_t*)(sm + 8192);
  float* mu  = sm + 12288;
  float* nrm = sm + 12352;

  const int b = blockIdx.x;
  const int t = threadIdx.x;
  const int w = t >> 6, lane = t & 63;
  const int lr = lane & 15, ko = lane >> 4;
  const float beta = betap[0];
  const float* whb = Wh + (size_t)b * N_ * F_;

  // ---- phase 1: row means ----
  {
    int n = t >> 2, q = t & 3;
    const float* row = whb + n * F_ + q * 128;
    float s = 0.f;
#pragma unroll
    for (int i = 0; i < 32; ++i) {
      float4 v = *(const float4*)(row + i * 4);
      s += v.x + v.y + v.z + v.w;
    }
    s += __shfl_xor(s, 1);
    s += __shfl_xor(s, 2);
    if (q == 0) mu[n] = s * (1.f / F_);
  }
  __syncthreads();

  // ---- phase 2: cov = Xm @ Xm^T via MFMA, 4 k-chunks of 128 ----
  f32x4 covA[4];
#pragma unroll
  for (int j = 0; j < 4; ++j) covA[j] = (f32x4){0.f, 0.f, 0.f, 0.f};

#pragma unroll 1
  for (int c = 0; c < 4; ++c) {
    // stage centered, x16, split chunk [64][128]
#pragma unroll
    for (int i = 0; i < 8; ++i) {
      int id = t + 256 * i;
      int n = id >> 5, c4 = id & 31;
      float4 v = *(const float4*)(whb + n * F_ + c * 128 + c4 * 4);
      float m_ = mu[n];
      float x0 = (v.x - m_) * 16.f, x1 = (v.y - m_) * 16.f;
      float x2 = (v.z - m_) * 16.f, x3 = (v.w - m_) * 16.f;
      half4 hh, hl;
      hh[0] = (half_t)x0; hl[0] = (half_t)(x0 - (float)hh[0]);
      hh[1] = (half_t)x1; hl[1] = (half_t)(x1 - (float)hh[1]);
      hh[2] = (half_t)x2; hl[2] = (half_t)(x2 - (float)hh[2]);
      hh[3] = (half_t)x3; hl[3] = (half_t)(x3 - (float)hh[3]);
      int ad = n * 128 + (((c4 >> 1) ^ (n & 7)) << 3) + (c4 & 1) * 4;
      *(half4*)&xm_h[ad] = hh;
      *(half4*)&xm_l[ad] = hl;
    }
    __syncthreads();
#pragma unroll
    for (int s = 0; s < 4; ++s) {
      int ra = w * 16 + lr;
      half8 ah = *(const half8*)&xm_h[XMI(ra, (s * 4 + ko) * 8)];
      half8 al = *(const half8*)&xm_l[XMI(ra, (s * 4 + ko) * 8)];
#pragma unroll
      for (int j = 0; j < 4; ++j) {
        int rb = j * 16 + lr;
        half8 bh = *(const half8*)&xm_h[XMI(rb, (s * 4 + ko) * 8)];
        half8 bl = *(const half8*)&xm_l[XMI(rb, (s * 4 + ko) * 8)];
        covA[j] = __builtin_amdgcn_mfma_f32_16x16x32_f16(ah, bh, covA[j], 0, 0, 0);
        covA[j] = __builtin_amdgcn_mfma_f32_16x16x32_f16(ah, bl, covA[j], 0, 0, 0);
        covA[j] = __builtin_amdgcn_mfma_f32_16x16x32_f16(al, bh, covA[j], 0, 0, 0);
      }
    }
    __syncthreads();
  }

  // ---- phase 3: norms from diagonal ----
#pragma unroll
  for (int r = 0; r < 4; ++r)
    if (lr == 4 * ko + r) nrm[w * 16 + lr] = sqrtf(covA[w][r]);
  __syncthreads();

  // ---- phase 4: e = beta*|corr| in regs (C-layout) + split to LDS ----
  float e32[4][4];  // [m-tile][reg]
#pragma unroll
  for (int j = 0; j < 4; ++j) {
#pragma unroll
    for (int r = 0; r < 4; ++r) {
      int n = w * 16 + 4 * ko + r;
      int m = j * 16 + lr;
      float denom = nrm[n] * nrm[m] + 2.56e-6f;  // (16nrm)(16nrm)+256*1e-8
      float e = beta * fabsf(covA[j][r] / denom);
      e32[j][r] = e;
      float es = e * 16.f;
      half_t hh = (half_t)es;
      e_h[SQI(n, m)] = hh;
      e_l[SQI(n, m)] = (half_t)(es - (float)hh);
    }
  }
  __syncthreads();

  // ---- phase 5: MLP via MFMA, K-chunked over 4 j-chunks of 64 ----
  f32x4 adj[4];
#pragma unroll
  for (int j = 0; j < 4; ++j) adj[j] = (f32x4){0.f, 0.f, 0.f, 0.f};

#pragma unroll 1
  for (int jc = 0; jc < 4; ++jc) {
    // [ONLY CHANGE 1] stage A1^T chunk: ab[jl][m] = 64*A1[m][jc*64+jl]
    // column-read (lanes coalesced over jl) + conflict-free half8 store.
#pragma unroll
    for (int hf = 0; hf < 2; ++hf) {
      int mo = w + 4 * hf;          // m-octet 0..7
      int jl = lane;                // 0..63
      half8 hh, hl;
#pragma unroll
      for (int q = 0; q < 8; ++q) {
        float x = A1[(size_t)(mo * 8 + q) * 256 + jc * 64 + jl] * 64.f;
        half_t h = (half_t)x;
        hh[q] = h; hl[q] = (half_t)(x - (float)h);
      }
      int ad = jl * 64 + ((mo ^ (jl & 7)) << 3);
      *(half8*)&ab_h[ad] = hh;
      *(half8*)&ab_l[ad] = hl;
    }
    __syncthreads();

    // layer1: hid = relu(e @ A1chunk)
    f32x4 h1[4];
#pragma unroll
    for (int j = 0; j < 4; ++j) h1[j] = (f32x4){0.f, 0.f, 0.f, 0.f};
#pragma unroll
    for (int s = 0; s < 2; ++s) {
      int ra = w * 16 + lr;
      half8 ah = *(const half8*)&e_h[SQI(ra, (s * 4 + ko) * 8)];
      half8 al = *(const half8*)&e_l[SQI(ra, (s * 4 + ko) * 8)];
#pragma unroll
      for (int jt = 0; jt < 4; ++jt) {
        int jl = jt * 16 + lr;
        half8 bh = *(const half8*)&ab_h[SQI(jl, (s * 4 + ko) * 8)];
        half8 bl = *(const half8*)&ab_l[SQI(jl, (s * 4 + ko) * 8)];
        h1[jt] = __builtin_amdgcn_mfma_f32_16x16x32_f16(ah, bh, h1[jt], 0, 0, 0);
        h1[jt] = __builtin_amdgcn_mfma_f32_16x16x32_f16(ah, bl, h1[jt], 0, 0, 0);
        h1[jt] = __builtin_amdgcn_mfma_f32_16x16x32_f16(al, bh, h1[jt], 0, 0, 0);
      }
    }
    // relu + split -> hid (C-layout: col=lr -> j, row=4ko+r -> n-local)
#pragma unroll
    for (int jt = 0; jt < 4; ++jt) {
#pragma unroll
      for (int r = 0; r < 4; ++r) {
        float x = fmaxf(h1[jt][r], 0.f);
        int n = w * 16 + 4 * ko + r;
        int jl = jt * 16 + lr;
        half_t hh = (half_t)x;
        hid_h[SQI(n, jl)] = hh;
        hid_l[SQI(n, jl)] = (half_t)(x - (float)hh);
      }
    }
    __syncthreads();

    // [ONLY CHANGE 2] stage A2 chunk: ab[m][kl] = 64*A2[jc*64+kl][m]
#pragma unroll
    for (int hf = 0; hf < 2; ++hf) {
      int ko2 = w + 4 * hf;         // kl-octet 0..7
      int m = lane;                 // 0..63
      half8 hh, hl;
#pragma unroll
      for (int q = 0; q < 8; ++q) {
        float x = A2[(size_t)(jc * 64 + ko2 * 8 + q) * 64 + m] * 64.f;
        half_t h = (half_t)x;
        hh[q] = h; hl[q] = (half_t)(x - (float)h);
      }
      int ad = m * 64 + ((ko2 ^ (m & 7)) << 3);
      *(half8*)&ab_h[ad] = hh;
      *(half8*)&ab_l[ad] = hl;
    }
    __syncthreads();

    // layer2: adj += hid @ A2chunk
#pragma unroll
    for (int s = 0; s < 2; ++s) {
      int ra = w * 16 + lr;
      half8 ah = *(const half8*)&hid_h[SQI(ra, (s * 4 + ko) * 8)];
      half8 al = *(const half8*)&hid_l[SQI(ra, (s * 4 + ko) * 8)];
#pragma unroll
      for (int mt = 0; mt < 4; ++mt) {
        int m = mt * 16 + lr;
        half8 bh = *(const half8*)&ab_h[SQI(m, (s * 4 + ko) * 8)];
        half8 bl = *(const half8*)&ab_l[SQI(m, (s * 4 + ko) * 8)];
        adj[mt] = __builtin_amdgcn_mfma_f32_16x16x32_f16(ah, bh, adj[mt], 0, 0, 0);
        adj[mt] = __builtin_amdgcn_mfma_f32_16x16x32_f16(ah, bl, adj[mt], 0, 0, 0);
        adj[mt] = __builtin_amdgcn_mfma_f32_16x16x32_f16(al, bh, adj[mt], 0, 0, 0);
      }
    }
    __syncthreads();
  }

  // ---- phase 6: mask + row-softmax in regs, split probs -> at_hl ----
  {
    float p[4][4];
#pragma unroll
    for (int r = 0; r < 4; ++r) {
      float mx = -3.0e38f;
#pragma unroll
      for (int mt = 0; mt < 4; ++mt) {
        float pre = e32[mt][r] + adj[mt][r] * (1.f / 65536.f);
        p[mt][r] = (pre > 0.f) ? e32[mt][r] : -1e12f;
        mx = fmaxf(mx, p[mt][r]);
      }
      mx = fmaxf(mx, __shfl_xor(mx, 1));
      mx = fmaxf(mx, __shfl_xor(mx, 2));
      mx = fmaxf(mx, __shfl_xor(mx, 4));
      mx = fmaxf(mx, __shfl_xor(mx, 8));
      float ssum = 0.f;
#pragma unroll
      for (int mt = 0; mt < 4; ++mt) {
        p[mt][r] = expf(p[mt][r] - mx);
        ssum += p[mt][r];
      }
      ssum += __shfl_xor(ssum, 1);
      ssum += __shfl_xor(ssum, 2);
      ssum += __shfl_xor(ssum, 4);
      ssum += __shfl_xor(ssum, 8);
      float inv = 1.f / ssum;
      int n = w * 16 + 4 * ko + r;
#pragma unroll
      for (int mt = 0; mt < 4; ++mt) {
        float pv = p[mt][r] * inv;
        int m = mt * 16 + lr;
        half_t hh = (half_t)pv;
        at_h[SQI(n, m)] = hh;
        at_l[SQI(n, m)] = (half_t)(pv - (float)hh);
      }
    }
  }

  // ---- phase 7: out = attn @ Wh via MFMA, 4 f-chunks of 128 ----
#pragma unroll 1
  for (int fc = 0; fc < 4; ++fc) {
    __syncthreads();  // at_hl writes done / previous chunk reads done
    // stage Wh chunk transposed+split: wt[f_local][m]
#pragma unroll
    for (int i = 0; i < 8; ++i) {
      int id = t + 256 * i;
      int m = id >> 5, c4 = id & 31;
      float4 v = *(const float4*)(whb + m * F_ + fc * 128 + c4 * 4);
#pragma unroll
      for (int q = 0; q < 4; ++q) {
        float x = ((const float*)&v)[q];
        half_t hh = (half_t)x;
        int f = c4 * 4 + q;
        int ad = f * 64 + ((((m >> 3) ^ (f & 7))) << 3) + (m & 7);
        wt_h[ad] = hh;
        wt_l[ad] = (half_t)(x - (float)hh);
      }
    }
    __syncthreads();

    half8 aah[2], aal[2];
#pragma unroll
    for (int s = 0; s < 2; ++s) {
      int n = w * 16 + lr;
      aah[s] = *(const half8*)&at_h[SQI(n, (s * 4 + ko) * 8)];
      aal[s] = *(const half8*)&at_l[SQI(n, (s * 4 + ko) * 8)];
    }
#pragma unroll
    for (int ft = 0; ft < 8; ++ft) {
      f32x4 po = (f32x4){0.f, 0.f, 0.f, 0.f};
#pragma unroll
      for (int s = 0; s < 2; ++s) {
        int fl = ft * 16 + lr;
        int ad = fl * 64 + (((((s * 4 + ko)) ^ (fl & 7))) << 3);
        half8 bh = *(const half8*)&wt_h[ad];
        half8 bl = *(const half8*)&wt_l[ad];
        po = __builtin_amdgcn_mfma_f32_16x16x32_f16(aah[s], bh, po, 0, 0, 0);
        po = __builtin_amdgcn_mfma_f32_16x16x32_f16(aah[s], bl, po, 0, 0, 0);
        po = __builtin_amdgcn_mfma_f32_16x16x32_f16(aal[s], bh, po, 0, 0, 0);
      }
      int fg = fc * 128 + ft * 16 + lr;
#pragma unroll
      for (int r = 0; r < 4; ++r) {
        int n = w * 16 + 4 * ko + r;
        out[(size_t)b * N_ * F_ + n * F_ + fg] = po[r];
      }
    }
  }
}

extern "C" void kernel_launch(void* const* d_in, const int* in_sizes, int n_in,
                              void* d_out, int out_size, void* d_ws, size_t ws_size,
                              hipStream_t stream) {
  const float* h    = (const float*)d_in[0];
  const float* W    = (const float*)d_in[1];
  const float* beta = (const float*)d_in[2];
  const float* A1   = (const float*)d_in[3];
  const float* A2   = (const float*)d_in[4];
  float* out = (float*)d_out;
  float* Wh  = (float*)d_ws;  // 128 MiB workspace

  half_t* wt_hi = (half_t*)d_out;
  half_t* wt_lo = wt_hi + 512 * 512;

  k_split_w<<<1024, 256, 0, stream>>>(W, wt_hi, wt_lo);
  k_wh<<<2048, 256, 0, stream>>>(h, wt_hi, wt_lo, Wh);
  k_attn<<<B_, 256, 0, stream>>>(Wh, A1, A2, beta, out);
}

// Round 10
// 278.992 us; speedup vs baseline: 3.6573x; 1.0720x over previous
//
#include <hip/hip_runtime.h>
#include <math.h>

#define B_ 1024
#define N_ 64
#define F_ 512

typedef const __attribute__((address_space(1))) float* gptr_t;
typedef __attribute__((address_space(3))) float* lptr_t;
typedef _Float16 half_t;
typedef half_t half8 __attribute__((ext_vector_type(8)));
typedef half_t half4 __attribute__((ext_vector_type(4)));
typedef float f32x4 __attribute__((ext_vector_type(4)));

__device__ __forceinline__ void gload16(const float* g, float* l) {
  __builtin_amdgcn_global_load_lds((gptr_t)g, (lptr_t)l, 16, 0, 0);
}

// swizzled LDS addresses (halves): octet-XOR keeps b128 frag reads 2-way max
#define XMI(n, f) ((n) * 128 + (((((f) >> 3) ^ ((n) >> 0 & 7))) << 3) + ((f) & 7))
#define SQI(n, m) ((n) * 64 + (((((m) >> 3) ^ ((n) & 7))) << 3) + ((m) & 7))

// ---------------------------------------------------------------------------
// Kernel 0: pre-split W (x512) into f16 hi/lo, transposed + swizzled.
// ---------------------------------------------------------------------------
__global__ __launch_bounds__(256) void k_split_w(const float* __restrict__ W,
                                                 half_t* __restrict__ wt_hi,
                                                 half_t* __restrict__ wt_lo) {
  int idx = blockIdx.x * 256 + threadIdx.x;  // 0..262143
  int k = idx >> 9, n = idx & 511;
  float wv = W[idx] * 512.0f;
  half_t hh = (half_t)wv;
  half_t hl = (half_t)(wv - (float)hh);
  int f = (n ^ (n >> 1)) & 3;
  int pos = ((k >> 3) & 3) ^ f;
  int addr = n * 512 + (k & ~31) + (pos << 3) + (k & 7);
  wt_hi[addr] = hh;
  wt_lo[addr] = hl;
}

// ---------------------------------------------------------------------------
// Kernel 1: Wh = h @ W via f16x3 split-MFMA (verbatim, proven).
// ---------------------------------------------------------------------------
__global__ __launch_bounds__(256, 2) void k_wh(const float* __restrict__ hA,
                                               const half_t* __restrict__ WTh,
                                               const half_t* __restrict__ WTl,
                                               float* __restrict__ Wh) {
  __shared__ float  As[2][128 * 32];
  __shared__ half_t Bh[2][128 * 32];
  __shared__ half_t Bl[2][128 * 32];

  const int bid = blockIdx.x;
  const int wg  = (bid & 7) * 256 + (bid >> 3);
  const int mt  = wg >> 2;
  const int nt  = wg & 3;
  const int t = threadIdx.x;
  const int w = t >> 6, lane = t & 63;
  const int wr = w >> 1, wc = w & 1;
  const int lr = lane & 15, ko = lane >> 4;

  const float* Ab = hA + (size_t)mt * 128 * F_;
  const int n0 = nt * 128;

  int Asrc[4], Alds[4];
#pragma unroll
  for (int i = 0; i < 4; ++i) {
    int s = t + 256 * i;
    int row = s >> 3, j = s & 7;
    int jg = j ^ (row & 7);
    Asrc[i] = row * F_ + jg * 4;
    Alds[i] = s * 4;
  }
  int Bsrc[2], Blds[2];
#pragma unroll
  for (int i = 0; i < 2; ++i) {
    int s = t + 256 * i;
    int n = s >> 2, sl = s & 3;
    Bsrc[i] = (n0 + n) * 512 + sl * 8;
    Blds[i] = s * 8;
  }

  f32x4 acc[4][4];
#pragma unroll
  for (int i = 0; i < 4; ++i)
#pragma unroll
    for (int j = 0; j < 4; ++j) acc[i][j] = (f32x4){0.f, 0.f, 0.f, 0.f};

#define STAGE(buf, k0)                                                       \
  do {                                                                       \
    _Pragma("unroll") for (int i_ = 0; i_ < 4; ++i_)                         \
        gload16(Ab + (size_t)(k0) + Asrc[i_], &As[buf][Alds[i_]]);           \
    _Pragma("unroll") for (int i_ = 0; i_ < 2; ++i_)                         \
        gload16((const float*)(WTh + (size_t)(k0) + Bsrc[i_]),               \
                (float*)&Bh[buf][Blds[i_]]);                                 \
    _Pragma("unroll") for (int i_ = 0; i_ < 2; ++i_)                         \
        gload16((const float*)(WTl + (size_t)(k0) + Bsrc[i_]),               \
                (float*)&Bl[buf][Blds[i_]]);                                 \
  } while (0)

#define COMPUTE(buf)                                                         \
  do {                                                                       \
    half8 bhf[4], blf[4];                                                    \
    _Pragma("unroll") for (int j = 0; j < 4; ++j) {                          \
      int nb = wc * 64 + j * 16 + lr;                                        \
      int p = ko ^ ((nb ^ (nb >> 1)) & 3);                                   \
      bhf[j] = *(const half8*)&Bh[buf][nb * 32 + p * 8];                     \
      blf[j] = *(const half8*)&Bl[buf][nb * 32 + p * 8];                     \
    }                                                                        \
    _Pragma("unroll") for (int i = 0; i < 4; ++i) {                          \
      int r = wr * 64 + i * 16 + lr;                                         \
      int p0 = (2 * ko) ^ (r & 7), p1 = (2 * ko + 1) ^ (r & 7);              \
      f32x4 x0 = *(const f32x4*)&As[buf][r * 32 + p0 * 4];                   \
      f32x4 x1 = *(const f32x4*)&As[buf][r * 32 + p1 * 4];                   \
      half8 ah, al;                                                          \
      _Pragma("unroll") for (int q = 0; q < 4; ++q) {                        \
        float xs = x0[q] * 16.0f;                                            \
        half_t hh = (half_t)xs;                                              \
        ah[q] = hh; al[q] = (half_t)(xs - (float)hh);                        \
      }                                                                      \
      _Pragma("unroll") for (int q = 0; q < 4; ++q) {                        \
        float xs = x1[q] * 16.0f;                                            \
        half_t hh = (half_t)xs;                                              \
        ah[4 + q] = hh; al[4 + q] = (half_t)(xs - (float)hh);                \
      }                                                                      \
      _Pragma("unroll") for (int j = 0; j < 4; ++j) {                        \
        acc[i][j] = __builtin_amdgcn_mfma_f32_16x16x32_f16(ah, bhf[j],       \
                                                           acc[i][j], 0, 0, 0); \
        acc[i][j] = __builtin_amdgcn_mfma_f32_16x16x32_f16(ah, blf[j],       \
                                                           acc[i][j], 0, 0, 0); \
        acc[i][j] = __builtin_amdgcn_mfma_f32_16x16x32_f16(al, bhf[j],       \
                                                           acc[i][j], 0, 0, 0); \
      }                                                                      \
    }                                                                        \
  } while (0)

  STAGE(0, 0);
  __syncthreads();
#pragma unroll 1
  for (int kt = 0; kt < 16; ++kt) {
    int cur = kt & 1;
    if (kt < 15) STAGE(cur ^ 1, (kt + 1) * 32);
    COMPUTE(cur);
    __syncthreads();
  }

  const float sc = 1.0f / 8192.0f;
  float* whb = Wh + ((size_t)mt * 128 + wr * 64) * F_ + n0 + wc * 64;
#pragma unroll
  for (int i = 0; i < 4; ++i) {
#pragma unroll
    for (int rr = 0; rr < 4; ++rr) {
      int row = i * 16 + ko * 4 + rr;
#pragma unroll
      for (int j = 0; j < 4; ++j)
        whb[row * F_ + j * 16 + lr] = acc[i][j][rr] * sc;
    }
  }
#undef STAGE
#undef COMPUTE
}

// ---------------------------------------------------------------------------
// Kernel 2: round-9 k_attn verbatim, with EXACTLY ONE change: phase-7 Wh^T
// staging uses column reads + conflict-free half8 stores (bit-identical LDS
// content to the scalar original).
// ---------------------------------------------------------------------------
__global__ __launch_bounds__(256) void k_attn(const float* __restrict__ Wh,
                                              const float* __restrict__ A1,
                                              const float* __restrict__ A2,
                                              const float* __restrict__ betap,
                                              float* __restrict__ out) {
  __shared__ float sm[12416];
  half_t* e_h   = (half_t*)sm;
  half_t* e_l   = e_h + 4096;
  half_t* xm_h  = (half_t*)(sm + 4096);
  half_t* xm_l  = xm_h + 8192;
  half_t* hid_h = (half_t*)(sm + 4096);
  half_t* hid_l = (half_t*)(sm + 6144);
  half_t* ab_h  = (half_t*)(sm + 8192);
  half_t* ab_l  = (half_t*)(sm + 10240);
  half_t* at_h  = (half_t*)sm;
  half_t* at_l  = at_h + 4096;
  half_t* wt_h  = (half_t*)(sm + 4096);
  half_t* wt_l  = (half_t*)(sm + 8192);
  float* mu  = sm + 12288;
  float* nrm = sm + 12352;

  const int b = blockIdx.x;
  const int t = threadIdx.x;
  const int w = t >> 6, lane = t & 63;
  const int lr = lane & 15, ko = lane >> 4;
  const float beta = betap[0];
  const float* whb = Wh + (size_t)b * N_ * F_;

  // ---- phase 1: row means ----
  {
    int n = t >> 2, q = t & 3;
    const float* row = whb + n * F_ + q * 128;
    float s = 0.f;
#pragma unroll
    for (int i = 0; i < 32; ++i) {
      float4 v = *(const float4*)(row + i * 4);
      s += v.x + v.y + v.z + v.w;
    }
    s += __shfl_xor(s, 1);
    s += __shfl_xor(s, 2);
    if (q == 0) mu[n] = s * (1.f / F_);
  }
  __syncthreads();

  // ---- phase 2: cov = Xm @ Xm^T via MFMA, 4 k-chunks of 128 ----
  f32x4 covA[4];
#pragma unroll
  for (int j = 0; j < 4; ++j) covA[j] = (f32x4){0.f, 0.f, 0.f, 0.f};

#pragma unroll 1
  for (int c = 0; c < 4; ++c) {
    // stage centered, x16, split chunk [64][128]
#pragma unroll
    for (int i = 0; i < 8; ++i) {
      int id = t + 256 * i;
      int n = id >> 5, c4 = id & 31;
      float4 v = *(const float4*)(whb + n * F_ + c * 128 + c4 * 4);
      float m_ = mu[n];
      float x0 = (v.x - m_) * 16.f, x1 = (v.y - m_) * 16.f;
      float x2 = (v.z - m_) * 16.f, x3 = (v.w - m_) * 16.f;
      half4 hh, hl;
      hh[0] = (half_t)x0; hl[0] = (half_t)(x0 - (float)hh[0]);
      hh[1] = (half_t)x1; hl[1] = (half_t)(x1 - (float)hh[1]);
      hh[2] = (half_t)x2; hl[2] = (half_t)(x2 - (float)hh[2]);
      hh[3] = (half_t)x3; hl[3] = (half_t)(x3 - (float)hh[3]);
      int ad = n * 128 + (((c4 >> 1) ^ (n & 7)) << 3) + (c4 & 1) * 4;
      *(half4*)&xm_h[ad] = hh;
      *(half4*)&xm_l[ad] = hl;
    }
    __syncthreads();
#pragma unroll
    for (int s = 0; s < 4; ++s) {
      int ra = w * 16 + lr;
      half8 ah = *(const half8*)&xm_h[XMI(ra, (s * 4 + ko) * 8)];
      half8 al = *(const half8*)&xm_l[XMI(ra, (s * 4 + ko) * 8)];
#pragma unroll
      for (int j = 0; j < 4; ++j) {
        int rb = j * 16 + lr;
        half8 bh = *(const half8*)&xm_h[XMI(rb, (s * 4 + ko) * 8)];
        half8 bl = *(const half8*)&xm_l[XMI(rb, (s * 4 + ko) * 8)];
        covA[j] = __builtin_amdgcn_mfma_f32_16x16x32_f16(ah, bh, covA[j], 0, 0, 0);
        covA[j] = __builtin_amdgcn_mfma_f32_16x16x32_f16(ah, bl, covA[j], 0, 0, 0);
        covA[j] = __builtin_amdgcn_mfma_f32_16x16x32_f16(al, bh, covA[j], 0, 0, 0);
      }
    }
    __syncthreads();
  }

  // ---- phase 3: norms from diagonal ----
#pragma unroll
  for (int r = 0; r < 4; ++r)
    if (lr == 4 * ko + r) nrm[w * 16 + lr] = sqrtf(covA[w][r]);
  __syncthreads();

  // ---- phase 4: e = beta*|corr| in regs (C-layout) + split to LDS ----
  float e32[4][4];  // [m-tile][reg]
#pragma unroll
  for (int j = 0; j < 4; ++j) {
#pragma unroll
    for (int r = 0; r < 4; ++r) {
      int n = w * 16 + 4 * ko + r;
      int m = j * 16 + lr;
      float denom = nrm[n] * nrm[m] + 2.56e-6f;  // (16nrm)(16nrm)+256*1e-8
      float e = beta * fabsf(covA[j][r] / denom);
      e32[j][r] = e;
      float es = e * 16.f;
      half_t hh = (half_t)es;
      e_h[SQI(n, m)] = hh;
      e_l[SQI(n, m)] = (half_t)(es - (float)hh);
    }
  }
  __syncthreads();

  // ---- phase 5: MLP via MFMA, K-chunked over 4 j-chunks of 64 ----
  f32x4 adj[4];
#pragma unroll
  for (int j = 0; j < 4; ++j) adj[j] = (f32x4){0.f, 0.f, 0.f, 0.f};

#pragma unroll 1
  for (int jc = 0; jc < 4; ++jc) {
    // stage A1^T chunk: ab[jl][m] = 64*A1[m][jc*64+jl]
#pragma unroll
    for (int hf = 0; hf < 2; ++hf) {
      int mo = w + 4 * hf;          // m-octet 0..7
      int jl = lane;                // 0..63
      half8 hh, hl;
#pragma unroll
      for (int q = 0; q < 8; ++q) {
        float x = A1[(size_t)(mo * 8 + q) * 256 + jc * 64 + jl] * 64.f;
        half_t h = (half_t)x;
        hh[q] = h; hl[q] = (half_t)(x - (float)h);
      }
      int ad = jl * 64 + ((mo ^ (jl & 7)) << 3);
      *(half8*)&ab_h[ad] = hh;
      *(half8*)&ab_l[ad] = hl;
    }
    __syncthreads();

    // layer1: hid = relu(e @ A1chunk)
    f32x4 h1[4];
#pragma unroll
    for (int j = 0; j < 4; ++j) h1[j] = (f32x4){0.f, 0.f, 0.f, 0.f};
#pragma unroll
    for (int s = 0; s < 2; ++s) {
      int ra = w * 16 + lr;
      half8 ah = *(const half8*)&e_h[SQI(ra, (s * 4 + ko) * 8)];
      half8 al = *(const half8*)&e_l[SQI(ra, (s * 4 + ko) * 8)];
#pragma unroll
      for (int jt = 0; jt < 4; ++jt) {
        int jl = jt * 16 + lr;
        half8 bh = *(const half8*)&ab_h[SQI(jl, (s * 4 + ko) * 8)];
        half8 bl = *(const half8*)&ab_l[SQI(jl, (s * 4 + ko) * 8)];
        h1[jt] = __builtin_amdgcn_mfma_f32_16x16x32_f16(ah, bh, h1[jt], 0, 0, 0);
        h1[jt] = __builtin_amdgcn_mfma_f32_16x16x32_f16(ah, bl, h1[jt], 0, 0, 0);
        h1[jt] = __builtin_amdgcn_mfma_f32_16x16x32_f16(al, bh, h1[jt], 0, 0, 0);
      }
    }
    // relu + split -> hid (C-layout: col=lr -> j, row=4ko+r -> n-local)
#pragma unroll
    for (int jt = 0; jt < 4; ++jt) {
#pragma unroll
      for (int r = 0; r < 4; ++r) {
        float x = fmaxf(h1[jt][r], 0.f);
        int n = w * 16 + 4 * ko + r;
        int jl = jt * 16 + lr;
        half_t hh = (half_t)x;
        hid_h[SQI(n, jl)] = hh;
        hid_l[SQI(n, jl)] = (half_t)(x - (float)hh);
      }
    }
    __syncthreads();

    // stage A2 chunk: ab[m][kl] = 64*A2[jc*64+kl][m]
#pragma unroll
    for (int hf = 0; hf < 2; ++hf) {
      int ko2 = w + 4 * hf;         // kl-octet 0..7
      int m = lane;                 // 0..63
      half8 hh, hl;
#pragma unroll
      for (int q = 0; q < 8; ++q) {
        float x = A2[(size_t)(jc * 64 + ko2 * 8 + q) * 64 + m] * 64.f;
        half_t h = (half_t)x;
        hh[q] = h; hl[q] = (half_t)(x - (float)h);
      }
      int ad = m * 64 + ((ko2 ^ (m & 7)) << 3);
      *(half8*)&ab_h[ad] = hh;
      *(half8*)&ab_l[ad] = hl;
    }
    __syncthreads();

    // layer2: adj += hid @ A2chunk
#pragma unroll
    for (int s = 0; s < 2; ++s) {
      int ra = w * 16 + lr;
      half8 ah = *(const half8*)&hid_h[SQI(ra, (s * 4 + ko) * 8)];
      half8 al = *(const half8*)&hid_l[SQI(ra, (s * 4 + ko) * 8)];
#pragma unroll
      for (int mt = 0; mt < 4; ++mt) {
        int m = mt * 16 + lr;
        half8 bh = *(const half8*)&ab_h[SQI(m, (s * 4 + ko) * 8)];
        half8 bl = *(const half8*)&ab_l[SQI(m, (s * 4 + ko) * 8)];
        adj[mt] = __builtin_amdgcn_mfma_f32_16x16x32_f16(ah, bh, adj[mt], 0, 0, 0);
        adj[mt] = __builtin_amdgcn_mfma_f32_16x16x32_f16(ah, bl, adj[mt], 0, 0, 0);
        adj[mt] = __builtin_amdgcn_mfma_f32_16x16x32_f16(al, bh, adj[mt], 0, 0, 0);
      }
    }
    __syncthreads();
  }

  // ---- phase 6: mask + row-softmax in regs, split probs -> at_hl ----
  {
    float p[4][4];
#pragma unroll
    for (int r = 0; r < 4; ++r) {
      float mx = -3.0e38f;
#pragma unroll
      for (int mt = 0; mt < 4; ++mt) {
        float pre = e32[mt][r] + adj[mt][r] * (1.f / 65536.f);
        p[mt][r] = (pre > 0.f) ? e32[mt][r] : -1e12f;
        mx = fmaxf(mx, p[mt][r]);
      }
      mx = fmaxf(mx, __shfl_xor(mx, 1));
      mx = fmaxf(mx, __shfl_xor(mx, 2));
      mx = fmaxf(mx, __shfl_xor(mx, 4));
      mx = fmaxf(mx, __shfl_xor(mx, 8));
      float ssum = 0.f;
#pragma unroll
      for (int mt = 0; mt < 4; ++mt) {
        p[mt][r] = expf(p[mt][r] - mx);
        ssum += p[mt][r];
      }
      ssum += __shfl_xor(ssum, 1);
      ssum += __shfl_xor(ssum, 2);
      ssum += __shfl_xor(ssum, 4);
      ssum += __shfl_xor(ssum, 8);
      float inv = 1.f / ssum;
      int n = w * 16 + 4 * ko + r;
#pragma unroll
      for (int mt = 0; mt < 4; ++mt) {
        float pv = p[mt][r] * inv;
        int m = mt * 16 + lr;
        half_t hh = (half_t)pv;
        at_h[SQI(n, m)] = hh;
        at_l[SQI(n, m)] = (half_t)(pv - (float)hh);
      }
    }
  }

  // ---- phase 7: out = attn @ Wh via MFMA, 4 f-chunks of 128 ----
  const int fl0 = t & 127;   // f-local row 0..127
  const int moB = t >> 7;    // m-octet base 0..1
#pragma unroll 1
  for (int fc = 0; fc < 4; ++fc) {
    __syncthreads();  // at_hl writes done / previous chunk reads done
    // [ONLY CHANGE] stage wt[fl][m] = Wh[m][fc*128+fl]: coalesced column
    // reads + conflict-free half8 stores (bit-identical LDS content).
#pragma unroll
    for (int i = 0; i < 4; ++i) {
      int mo = moB + 2 * i;  // m-octet 0..7
      half8 hh, hl;
#pragma unroll
      for (int q = 0; q < 8; ++q) {
        float x = whb[(size_t)(mo * 8 + q) * F_ + fc * 128 + fl0];
        half_t h = (half_t)x;
        hh[q] = h; hl[q] = (half_t)(x - (float)h);
      }
      int ad = fl0 * 64 + ((mo ^ (fl0 & 7)) << 3);
      *(half8*)&wt_h[ad] = hh;
      *(half8*)&wt_l[ad] = hl;
    }
    __syncthreads();

    half8 aah[2], aal[2];
#pragma unroll
    for (int s = 0; s < 2; ++s) {
      int n = w * 16 + lr;
      aah[s] = *(const half8*)&at_h[SQI(n, (s * 4 + ko) * 8)];
      aal[s] = *(const half8*)&at_l[SQI(n, (s * 4 + ko) * 8)];
    }
#pragma unroll
    for (int ft = 0; ft < 8; ++ft) {
      f32x4 po = (f32x4){0.f, 0.f, 0.f, 0.f};
#pragma unroll
      for (int s = 0; s < 2; ++s) {
        int fl = ft * 16 + lr;
        int ad = fl * 64 + (((((s * 4 + ko)) ^ (fl & 7))) << 3);
        half8 bh = *(const half8*)&wt_h[ad];
        half8 bl = *(const half8*)&wt_l[ad];
        po = __builtin_amdgcn_mfma_f32_16x16x32_f16(aah[s], bh, po, 0, 0, 0);
        po = __builtin_amdgcn_mfma_f32_16x16x32_f16(aah[s], bl, po, 0, 0, 0);
        po = __builtin_amdgcn_mfma_f32_16x16x32_f16(aal[s], bh, po, 0, 0, 0);
      }
      int fg = fc * 128 + ft * 16 + lr;
#pragma unroll
      for (int r = 0; r < 4; ++r) {
        int n = w * 16 + 4 * ko + r;
        out[(size_t)b * N_ * F_ + n * F_ + fg] = po[r];
      }
    }
  }
}

extern "C" void kernel_launch(void* const* d_in, const int* in_sizes, int n_in,
                              void* d_out, int out_size, void* d_ws, size_t ws_size,
                              hipStream_t stream) {
  const float* h    = (const float*)d_in[0];
  const float* W    = (const float*)d_in[1];
  const float* beta = (const float*)d_in[2];
  const float* A1   = (const float*)d_in[3];
  const float* A2   = (const float*)d_in[4];
  float* out = (float*)d_out;
  float* Wh  = (float*)d_ws;  // 128 MiB workspace

  half_t* wt_hi = (half_t*)d_out;
  half_t* wt_lo = wt_hi + 512 * 512;

  k_split_w<<<1024, 256, 0, stream>>>(W, wt_hi, wt_lo);
  k_wh<<<2048, 256, 0, stream>>>(h, wt_hi, wt_lo, Wh);
  k_attn<<<B_, 256, 0, stream>>>(Wh, A1, A2, beta, out);
}

// Round 11
// 278.966 us; speedup vs baseline: 3.6577x; 1.0001x over previous
//
#include <hip/hip_runtime.h>
#include <math.h>

#define B_ 1024
#define N_ 64
#define F_ 512

typedef const __attribute__((address_space(1))) float* gptr_t;
typedef __attribute__((address_space(3))) float* lptr_t;
typedef _Float16 half_t;
typedef half_t half8 __attribute__((ext_vector_type(8)));
typedef half_t half4 __attribute__((ext_vector_type(4)));
typedef float f32x4 __attribute__((ext_vector_type(4)));

__device__ __forceinline__ void gload16(const float* g, float* l) {
  __builtin_amdgcn_global_load_lds((gptr_t)g, (lptr_t)l, 16, 0, 0);
}

// swizzled LDS addresses (halves): octet-XOR keeps b128 frag reads 2-way max
#define XMI(n, f) ((n) * 128 + (((((f) >> 3) ^ ((n) >> 0 & 7))) << 3) + ((f) & 7))
#define SQI(n, m) ((n) * 64 + (((((m) >> 3) ^ ((n) & 7))) << 3) + ((m) & 7))

// ---------------------------------------------------------------------------
// Kernel 0: pre-split W (x512) into f16 hi/lo, transposed + swizzled.
// ---------------------------------------------------------------------------
__global__ __launch_bounds__(256) void k_split_w(const float* __restrict__ W,
                                                 half_t* __restrict__ wt_hi,
                                                 half_t* __restrict__ wt_lo) {
  int idx = blockIdx.x * 256 + threadIdx.x;  // 0..262143
  int k = idx >> 9, n = idx & 511;
  float wv = W[idx] * 512.0f;
  half_t hh = (half_t)wv;
  half_t hl = (half_t)(wv - (float)hh);
  int f = (n ^ (n >> 1)) & 3;
  int pos = ((k >> 3) & 3) ^ f;
  int addr = n * 512 + (k & ~31) + (pos << 3) + (k & 7);
  wt_hi[addr] = hh;
  wt_lo[addr] = hl;
}

// ---------------------------------------------------------------------------
// Kernel 1: Wh = h @ W via f16x3 split-MFMA. v2: A split ONCE at staging
// (global->reg float4, split in regs, half8 ds_write into swizzled Ah/Al),
// removing the duplicated per-COMPUTE split VALU. Math bit-identical.
// ---------------------------------------------------------------------------
__global__ __launch_bounds__(256, 2) void k_wh(const float* __restrict__ hA,
                                               const half_t* __restrict__ WTh,
                                               const half_t* __restrict__ WTl,
                                               float* __restrict__ Wh) {
  __shared__ half_t Ah[2][128 * 32];   // 8KB x2
  __shared__ half_t Alo[2][128 * 32];  // 8KB x2
  __shared__ half_t Bh[2][128 * 32];   // 8KB x2
  __shared__ half_t Bl[2][128 * 32];   // 8KB x2   -> 64KB total

  const int bid = blockIdx.x;
  const int wg  = (bid & 7) * 256 + (bid >> 3);
  const int mt  = wg >> 2;
  const int nt  = wg & 3;
  const int t = threadIdx.x;
  const int w = t >> 6, lane = t & 63;
  const int wr = w >> 1, wc = w & 1;
  const int lr = lane & 15, ko = lane >> 4;

  const float* Ab = hA + (size_t)mt * 128 * F_;
  const int n0 = nt * 128;

  // A staging: thread owns 2 (row, k-octet) cells; coalesced 32B global read.
  int Arow[2], Aoct[2], Aad[2];
#pragma unroll
  for (int i = 0; i < 2; ++i) {
    int id = t + 256 * i;
    int row = id >> 2, oct = id & 3;
    Arow[i] = row;
    Aoct[i] = oct;
    Aad[i] = row * 32 + ((oct ^ ((row ^ (row >> 1)) & 3)) << 3);
  }
  // B staging via global_load_lds (unchanged, proven).
  int Bsrc[2], Blds[2];
#pragma unroll
  for (int i = 0; i < 2; ++i) {
    int s = t + 256 * i;
    int n = s >> 2, sl = s & 3;
    Bsrc[i] = (n0 + n) * 512 + sl * 8;
    Blds[i] = s * 8;
  }

  f32x4 acc[4][4];
#pragma unroll
  for (int i = 0; i < 4; ++i)
#pragma unroll
    for (int j = 0; j < 4; ++j) acc[i][j] = (f32x4){0.f, 0.f, 0.f, 0.f};

  float4 areg[2][2];

#define LOADA(k0)                                                            \
  do {                                                                       \
    _Pragma("unroll") for (int i_ = 0; i_ < 2; ++i_) {                       \
      const float* p = Ab + (size_t)Arow[i_] * F_ + (k0) + Aoct[i_] * 8;     \
      areg[i_][0] = *(const float4*)p;                                       \
      areg[i_][1] = *(const float4*)(p + 4);                                 \
    }                                                                        \
  } while (0)

#define WRITEA(buf)                                                          \
  do {                                                                       \
    _Pragma("unroll") for (int i_ = 0; i_ < 2; ++i_) {                       \
      half8 hh, hl;                                                          \
      _Pragma("unroll") for (int q = 0; q < 4; ++q) {                        \
        float xs = ((const float*)&areg[i_][0])[q] * 16.0f;                  \
        half_t h = (half_t)xs;                                               \
        hh[q] = h; hl[q] = (half_t)(xs - (float)h);                          \
      }                                                                      \
      _Pragma("unroll") for (int q = 0; q < 4; ++q) {                        \
        float xs = ((const float*)&areg[i_][1])[q] * 16.0f;                  \
        half_t h = (half_t)xs;                                               \
        hh[4 + q] = h; hl[4 + q] = (half_t)(xs - (float)h);                  \
      }                                                                      \
      *(half8*)&Ah[buf][Aad[i_]] = hh;                                       \
      *(half8*)&Alo[buf][Aad[i_]] = hl;                                      \
    }                                                                        \
  } while (0)

#define STAGEB(buf, k0)                                                      \
  do {                                                                       \
    _Pragma("unroll") for (int i_ = 0; i_ < 2; ++i_)                         \
        gload16((const float*)(WTh + (size_t)(k0) + Bsrc[i_]),               \
                (float*)&Bh[buf][Blds[i_]]);                                 \
    _Pragma("unroll") for (int i_ = 0; i_ < 2; ++i_)                         \
        gload16((const float*)(WTl + (size_t)(k0) + Bsrc[i_]),               \
                (float*)&Bl[buf][Blds[i_]]);                                 \
  } while (0)

#define COMPUTE(buf)                                                         \
  do {                                                                       \
    half8 bhf[4], blf[4];                                                    \
    _Pragma("unroll") for (int j = 0; j < 4; ++j) {                          \
      int nb = wc * 64 + j * 16 + lr;                                        \
      int p = ko ^ ((nb ^ (nb >> 1)) & 3);                                   \
      bhf[j] = *(const half8*)&Bh[buf][nb * 32 + p * 8];                     \
      blf[j] = *(const half8*)&Bl[buf][nb * 32 + p * 8];                     \
    }                                                                        \
    _Pragma("unroll") for (int i = 0; i < 4; ++i) {                          \
      int r = wr * 64 + i * 16 + lr;                                         \
      int pa = r * 32 + ((ko ^ ((r ^ (r >> 1)) & 3)) << 3);                  \
      half8 ah = *(const half8*)&Ah[buf][pa];                                \
      half8 al = *(const half8*)&Alo[buf][pa];                               \
      _Pragma("unroll") for (int j = 0; j < 4; ++j) {                        \
        acc[i][j] = __builtin_amdgcn_mfma_f32_16x16x32_f16(ah, bhf[j],       \
                                                           acc[i][j], 0, 0, 0); \
        acc[i][j] = __builtin_amdgcn_mfma_f32_16x16x32_f16(ah, blf[j],       \
                                                           acc[i][j], 0, 0, 0); \
        acc[i][j] = __builtin_amdgcn_mfma_f32_16x16x32_f16(al, bhf[j],       \
                                                           acc[i][j], 0, 0, 0); \
      }                                                                      \
    }                                                                        \
  } while (0)

  LOADA(0);
  STAGEB(0, 0);
  WRITEA(0);
  __syncthreads();
#pragma unroll 1
  for (int kt = 0; kt < 16; ++kt) {
    int cur = kt & 1;
    if (kt < 15) {
      LOADA((kt + 1) * 32);       // HBM latency hides under COMPUTE
      STAGEB(cur ^ 1, (kt + 1) * 32);
    }
    COMPUTE(cur);
    if (kt < 15) WRITEA(cur ^ 1); // write-late into the idle buffer
    __syncthreads();
  }

  const float sc = 1.0f / 8192.0f;
  float* whb = Wh + ((size_t)mt * 128 + wr * 64) * F_ + n0 + wc * 64;
#pragma unroll
  for (int i = 0; i < 4; ++i) {
#pragma unroll
    for (int rr = 0; rr < 4; ++rr) {
      int row = i * 16 + ko * 4 + rr;
#pragma unroll
      for (int j = 0; j < 4; ++j)
        whb[row * F_ + j * 16 + lr] = acc[i][j][rr] * sc;
    }
  }
#undef LOADA
#undef WRITEA
#undef STAGEB
#undef COMPUTE
}

// ---------------------------------------------------------------------------
// Kernel 2: round-10 k_attn verbatim (passing, 110 us).
// ---------------------------------------------------------------------------
__global__ __launch_bounds__(256) void k_attn(const float* __restrict__ Wh,
                                              const float* __restrict__ A1,
                                              const float* __restrict__ A2,
                                              const float* __restrict__ betap,
                                              float* __restrict__ out) {
  __shared__ float sm[12416];
  half_t* e_h   = (half_t*)sm;
  half_t* e_l   = e_h + 4096;
  half_t* xm_h  = (half_t*)(sm + 4096);
  half_t* xm_l  = xm_h + 8192;
  half_t* hid_h = (half_t*)(sm + 4096);
  half_t* hid_l = (half_t*)(sm + 6144);
  half_t* ab_h  = (half_t*)(sm + 8192);
  half_t* ab_l  = (half_t*)(sm + 10240);
  half_t* at_h  = (half_t*)sm;
  half_t* at_l  = at_h + 4096;
  half_t* wt_h  = (half_t*)(sm + 4096);
  half_t* wt_l  = (half_t*)(sm + 8192);
  float* mu  = sm + 12288;
  float* nrm = sm + 12352;

  const int b = blockIdx.x;
  const int t = threadIdx.x;
  const int w = t >> 6, lane = t & 63;
  const int lr = lane & 15, ko = lane >> 4;
  const float beta = betap[0];
  const float* whb = Wh + (size_t)b * N_ * F_;

  // ---- phase 1: row means ----
  {
    int n = t >> 2, q = t & 3;
    const float* row = whb + n * F_ + q * 128;
    float s = 0.f;
#pragma unroll
    for (int i = 0; i < 32; ++i) {
      float4 v = *(const float4*)(row + i * 4);
      s += v.x + v.y + v.z + v.w;
    }
    s += __shfl_xor(s, 1);
    s += __shfl_xor(s, 2);
    if (q == 0) mu[n] = s * (1.f / F_);
  }
  __syncthreads();

  // ---- phase 2: cov = Xm @ Xm^T via MFMA, 4 k-chunks of 128 ----
  f32x4 covA[4];
#pragma unroll
  for (int j = 0; j < 4; ++j) covA[j] = (f32x4){0.f, 0.f, 0.f, 0.f};

#pragma unroll 1
  for (int c = 0; c < 4; ++c) {
#pragma unroll
    for (int i = 0; i < 8; ++i) {
      int id = t + 256 * i;
      int n = id >> 5, c4 = id & 31;
      float4 v = *(const float4*)(whb + n * F_ + c * 128 + c4 * 4);
      float m_ = mu[n];
      float x0 = (v.x - m_) * 16.f, x1 = (v.y - m_) * 16.f;
      float x2 = (v.z - m_) * 16.f, x3 = (v.w - m_) * 16.f;
      half4 hh, hl;
      hh[0] = (half_t)x0; hl[0] = (half_t)(x0 - (float)hh[0]);
      hh[1] = (half_t)x1; hl[1] = (half_t)(x1 - (float)hh[1]);
      hh[2] = (half_t)x2; hl[2] = (half_t)(x2 - (float)hh[2]);
      hh[3] = (half_t)x3; hl[3] = (half_t)(x3 - (float)hh[3]);
      int ad = n * 128 + (((c4 >> 1) ^ (n & 7)) << 3) + (c4 & 1) * 4;
      *(half4*)&xm_h[ad] = hh;
      *(half4*)&xm_l[ad] = hl;
    }
    __syncthreads();
#pragma unroll
    for (int s = 0; s < 4; ++s) {
      int ra = w * 16 + lr;
      half8 ah = *(const half8*)&xm_h[XMI(ra, (s * 4 + ko) * 8)];
      half8 al = *(const half8*)&xm_l[XMI(ra, (s * 4 + ko) * 8)];
#pragma unroll
      for (int j = 0; j < 4; ++j) {
        int rb = j * 16 + lr;
        half8 bh = *(const half8*)&xm_h[XMI(rb, (s * 4 + ko) * 8)];
        half8 bl = *(const half8*)&xm_l[XMI(rb, (s * 4 + ko) * 8)];
        covA[j] = __builtin_amdgcn_mfma_f32_16x16x32_f16(ah, bh, covA[j], 0, 0, 0);
        covA[j] = __builtin_amdgcn_mfma_f32_16x16x32_f16(ah, bl, covA[j], 0, 0, 0);
        covA[j] = __builtin_amdgcn_mfma_f32_16x16x32_f16(al, bh, covA[j], 0, 0, 0);
      }
    }
    __syncthreads();
  }

  // ---- phase 3: norms from diagonal ----
#pragma unroll
  for (int r = 0; r < 4; ++r)
    if (lr == 4 * ko + r) nrm[w * 16 + lr] = sqrtf(covA[w][r]);
  __syncthreads();

  // ---- phase 4: e = beta*|corr| in regs (C-layout) + split to LDS ----
  float e32[4][4];  // [m-tile][reg]
#pragma unroll
  for (int j = 0; j < 4; ++j) {
#pragma unroll
    for (int r = 0; r < 4; ++r) {
      int n = w * 16 + 4 * ko + r;
      int m = j * 16 + lr;
      float denom = nrm[n] * nrm[m] + 2.56e-6f;  // (16nrm)(16nrm)+256*1e-8
      float e = beta * fabsf(covA[j][r] / denom);
      e32[j][r] = e;
      float es = e * 16.f;
      half_t hh = (half_t)es;
      e_h[SQI(n, m)] = hh;
      e_l[SQI(n, m)] = (half_t)(es - (float)hh);
    }
  }
  __syncthreads();

  // ---- phase 5: MLP via MFMA, K-chunked over 4 j-chunks of 64 ----
  f32x4 adj[4];
#pragma unroll
  for (int j = 0; j < 4; ++j) adj[j] = (f32x4){0.f, 0.f, 0.f, 0.f};

#pragma unroll 1
  for (int jc = 0; jc < 4; ++jc) {
    // stage A1^T chunk: ab[jl][m] = 64*A1[m][jc*64+jl]
#pragma unroll
    for (int hf = 0; hf < 2; ++hf) {
      int mo = w + 4 * hf;          // m-octet 0..7
      int jl = lane;                // 0..63
      half8 hh, hl;
#pragma unroll
      for (int q = 0; q < 8; ++q) {
        float x = A1[(size_t)(mo * 8 + q) * 256 + jc * 64 + jl] * 64.f;
        half_t h = (half_t)x;
        hh[q] = h; hl[q] = (half_t)(x - (float)h);
      }
      int ad = jl * 64 + ((mo ^ (jl & 7)) << 3);
      *(half8*)&ab_h[ad] = hh;
      *(half8*)&ab_l[ad] = hl;
    }
    __syncthreads();

    // layer1: hid = relu(e @ A1chunk)
    f32x4 h1[4];
#pragma unroll
    for (int j = 0; j < 4; ++j) h1[j] = (f32x4){0.f, 0.f, 0.f, 0.f};
#pragma unroll
    for (int s = 0; s < 2; ++s) {
      int ra = w * 16 + lr;
      half8 ah = *(const half8*)&e_h[SQI(ra, (s * 4 + ko) * 8)];
      half8 al = *(const half8*)&e_l[SQI(ra, (s * 4 + ko) * 8)];
#pragma unroll
      for (int jt = 0; jt < 4; ++jt) {
        int jl = jt * 16 + lr;
        half8 bh = *(const half8*)&ab_h[SQI(jl, (s * 4 + ko) * 8)];
        half8 bl = *(const half8*)&ab_l[SQI(jl, (s * 4 + ko) * 8)];
        h1[jt] = __builtin_amdgcn_mfma_f32_16x16x32_f16(ah, bh, h1[jt], 0, 0, 0);
        h1[jt] = __builtin_amdgcn_mfma_f32_16x16x32_f16(ah, bl, h1[jt], 0, 0, 0);
        h1[jt] = __builtin_amdgcn_mfma_f32_16x16x32_f16(al, bh, h1[jt], 0, 0, 0);
      }
    }
    // relu + split -> hid
#pragma unroll
    for (int jt = 0; jt < 4; ++jt) {
#pragma unroll
      for (int r = 0; r < 4; ++r) {
        float x = fmaxf(h1[jt][r], 0.f);
        int n = w * 16 + 4 * ko + r;
        int jl = jt * 16 + lr;
        half_t hh = (half_t)x;
        hid_h[SQI(n, jl)] = hh;
        hid_l[SQI(n, jl)] = (half_t)(x - (float)hh);
      }
    }
    __syncthreads();

    // stage A2 chunk: ab[m][kl] = 64*A2[jc*64+kl][m]
#pragma unroll
    for (int hf = 0; hf < 2; ++hf) {
      int ko2 = w + 4 * hf;         // kl-octet 0..7
      int m = lane;                 // 0..63
      half8 hh, hl;
#pragma unroll
      for (int q = 0; q < 8; ++q) {
        float x = A2[(size_t)(jc * 64 + ko2 * 8 + q) * 64 + m] * 64.f;
        half_t h = (half_t)x;
        hh[q] = h; hl[q] = (half_t)(x - (float)h);
      }
      int ad = m * 64 + ((ko2 ^ (m & 7)) << 3);
      *(half8*)&ab_h[ad] = hh;
      *(half8*)&ab_l[ad] = hl;
    }
    __syncthreads();

    // layer2: adj += hid @ A2chunk
#pragma unroll
    for (int s = 0; s < 2; ++s) {
      int ra = w * 16 + lr;
      half8 ah = *(const half8*)&hid_h[SQI(ra, (s * 4 + ko) * 8)];
      half8 al = *(const half8*)&hid_l[SQI(ra, (s * 4 + ko) * 8)];
#pragma unroll
      for (int mt = 0; mt < 4; ++mt) {
        int m = mt * 16 + lr;
        half8 bh = *(const half8*)&ab_h[SQI(m, (s * 4 + ko) * 8)];
        half8 bl = *(const half8*)&ab_l[SQI(m, (s * 4 + ko) * 8)];
        adj[mt] = __builtin_amdgcn_mfma_f32_16x16x32_f16(ah, bh, adj[mt], 0, 0, 0);
        adj[mt] = __builtin_amdgcn_mfma_f32_16x16x32_f16(ah, bl, adj[mt], 0, 0, 0);
        adj[mt] = __builtin_amdgcn_mfma_f32_16x16x32_f16(al, bh, adj[mt], 0, 0, 0);
      }
    }
    __syncthreads();
  }

  // ---- phase 6: mask + row-softmax in regs, split probs -> at_hl ----
  {
    float p[4][4];
#pragma unroll
    for (int r = 0; r < 4; ++r) {
      float mx = -3.0e38f;
#pragma unroll
      for (int mt = 0; mt < 4; ++mt) {
        float pre = e32[mt][r] + adj[mt][r] * (1.f / 65536.f);
        p[mt][r] = (pre > 0.f) ? e32[mt][r] : -1e12f;
        mx = fmaxf(mx, p[mt][r]);
      }
      mx = fmaxf(mx, __shfl_xor(mx, 1));
      mx = fmaxf(mx, __shfl_xor(mx, 2));
      mx = fmaxf(mx, __shfl_xor(mx, 4));
      mx = fmaxf(mx, __shfl_xor(mx, 8));
      float ssum = 0.f;
#pragma unroll
      for (int mt = 0; mt < 4; ++mt) {
        p[mt][r] = expf(p[mt][r] - mx);
        ssum += p[mt][r];
      }
      ssum += __shfl_xor(ssum, 1);
      ssum += __shfl_xor(ssum, 2);
      ssum += __shfl_xor(ssum, 4);
      ssum += __shfl_xor(ssum, 8);
      float inv = 1.f / ssum;
      int n = w * 16 + 4 * ko + r;
#pragma unroll
      for (int mt = 0; mt < 4; ++mt) {
        float pv = p[mt][r] * inv;
        int m = mt * 16 + lr;
        half_t hh = (half_t)pv;
        at_h[SQI(n, m)] = hh;
        at_l[SQI(n, m)] = (half_t)(pv - (float)hh);
      }
    }
  }

  // ---- phase 7: out = attn @ Wh via MFMA, 4 f-chunks of 128 ----
  const int fl0 = t & 127;   // f-local row 0..127
  const int moB = t >> 7;    // m-octet base 0..1
#pragma unroll 1
  for (int fc = 0; fc < 4; ++fc) {
    __syncthreads();
#pragma unroll
    for (int i = 0; i < 4; ++i) {
      int mo = moB + 2 * i;  // m-octet 0..7
      half8 hh, hl;
#pragma unroll
      for (int q = 0; q < 8; ++q) {
        float x = whb[(size_t)(mo * 8 + q) * F_ + fc * 128 + fl0];
        half_t h = (half_t)x;
        hh[q] = h; hl[q] = (half_t)(x - (float)h);
      }
      int ad = fl0 * 64 + ((mo ^ (fl0 & 7)) << 3);
      *(half8*)&wt_h[ad] = hh;
      *(half8*)&wt_l[ad] = hl;
    }
    __syncthreads();

    half8 aah[2], aal[2];
#pragma unroll
    for (int s = 0; s < 2; ++s) {
      int n = w * 16 + lr;
      aah[s] = *(const half8*)&at_h[SQI(n, (s * 4 + ko) * 8)];
      aal[s] = *(const half8*)&at_l[SQI(n, (s * 4 + ko) * 8)];
    }
#pragma unroll
    for (int ft = 0; ft < 8; ++ft) {
      f32x4 po = (f32x4){0.f, 0.f, 0.f, 0.f};
#pragma unroll
      for (int s = 0; s < 2; ++s) {
        int fl = ft * 16 + lr;
        int ad = fl * 64 + (((((s * 4 + ko)) ^ (fl & 7))) << 3);
        half8 bh = *(const half8*)&wt_h[ad];
        half8 bl = *(const half8*)&wt_l[ad];
        po = __builtin_amdgcn_mfma_f32_16x16x32_f16(aah[s], bh, po, 0, 0, 0);
        po = __builtin_amdgcn_mfma_f32_16x16x32_f16(aah[s], bl, po, 0, 0, 0);
        po = __builtin_amdgcn_mfma_f32_16x16x32_f16(aal[s], bh, po, 0, 0, 0);
      }
      int fg = fc * 128 + ft * 16 + lr;
#pragma unroll
      for (int r = 0; r < 4; ++r) {
        int n = w * 16 + 4 * ko + r;
        out[(size_t)b * N_ * F_ + n * F_ + fg] = po[r];
      }
    }
  }
}

extern "C" void kernel_launch(void* const* d_in, const int* in_sizes, int n_in,
                              void* d_out, int out_size, void* d_ws, size_t ws_size,
                              hipStream_t stream) {
  const float* h    = (const float*)d_in[0];
  const float* W    = (const float*)d_in[1];
  const float* beta = (const float*)d_in[2];
  const float* A1   = (const float*)d_in[3];
  const float* A2   = (const float*)d_in[4];
  float* out = (float*)d_out;
  float* Wh  = (float*)d_ws;  // 128 MiB workspace

  half_t* wt_hi = (half_t*)d_out;
  half_t* wt_lo = wt_hi + 512 * 512;

  k_split_w<<<1024, 256, 0, stream>>>(W, wt_hi, wt_lo);
  k_wh<<<2048, 256, 0, stream>>>(h, wt_hi, wt_lo, Wh);
  k_attn<<<B_, 256, 0, stream>>>(Wh, A1, A2, beta, out);
}